// Round 13
// baseline (1041.028 us; speedup 1.0000x reference)
//
#include <hip/hip_runtime.h>
#include <hip/hip_bf16.h>
#include <math.h>

#define BB 2
#define TT 2048
#define DD 768
#define HH 12
#define NTOK (BB*TT)   // 4096
#define VV 32000
#define NL 2

typedef __hip_bfloat16 bf16;
typedef __attribute__((ext_vector_type(8))) short bf16x8;
typedef __attribute__((ext_vector_type(4))) float f32x4;

typedef const __attribute__((address_space(1))) unsigned int* gas_u32;
typedef __attribute__((address_space(3))) unsigned int* las_u32;

__device__ __forceinline__ void gload16(const bf16* g, bf16* l) {
    __builtin_amdgcn_global_load_lds((gas_u32)g, (las_u32)l, 16, 0, 0);
}
__device__ __forceinline__ unsigned short f2bu(float f) {
    bf16 h = __float2bfloat16(f);
    return *reinterpret_cast<unsigned short*>(&h);
}

// ---------------- fused fp32 -> bf16 cast of ALL weights (one dispatch) ----------------
__global__ __launch_bounds__(256) void cast_all(
    const float* __restrict__ wte, const float* __restrict__ qkv_w,
    const float* __restrict__ proj_w, const float* __restrict__ fc_w,
    const float* __restrict__ fc2_w,
    bf16* __restrict__ o_wte, bf16* __restrict__ o_qkv, bf16* __restrict__ o_prj,
    bf16* __restrict__ o_fc, bf16* __restrict__ o_fc2)
{
    constexpr int N_WTE = VV * DD / 4;
    constexpr int N_QKV = NL * 3 * DD * DD / 4;
    constexpr int N_PRJ = NL * DD * DD / 4;
    constexpr int N_FC  = NL * 4 * DD * DD / 4;
    int g = blockIdx.x * 256 + threadIdx.x;
    const float* s; bf16* d;
    if (g < N_WTE) { s = wte; d = o_wte; }
    else if ((g -= N_WTE) < N_QKV) { s = qkv_w; d = o_qkv; }
    else if ((g -= N_QKV) < N_PRJ) { s = proj_w; d = o_prj; }
    else if ((g -= N_PRJ) < N_FC)  { s = fc_w;  d = o_fc; }
    else { g -= N_FC; s = fc2_w; d = o_fc2; }
    float4 v = reinterpret_cast<const float4*>(s)[g];
    ushort4 r;
    r.x = f2bu(v.x);
    r.y = f2bu(v.y);
    r.z = f2bu(v.z);
    r.w = f2bu(v.w);
    reinterpret_cast<ushort4*>(d)[g] = r;
}

// ---------------- embedding: x = wte[idx] + wpe[t] ----------------
__global__ void embed_k(const int* __restrict__ idx, const float* __restrict__ wte,
                        const float* __restrict__ wpe, float* __restrict__ x) {
    int i = blockIdx.x * 256 + threadIdx.x;          // over NTOK * (DD/4)
    int n = i / (DD/4), d4 = i - n * (DD/4);
    int tok = idx[n];
    int t = n & (TT - 1);
    float4 a = reinterpret_cast<const float4*>(wte + (size_t)tok * DD)[d4];
    float4 p = reinterpret_cast<const float4*>(wpe + (size_t)t * DD)[d4];
    float4 r; r.x = a.x+p.x; r.y = a.y+p.y; r.z = a.z+p.z; r.w = a.w+p.w;
    reinterpret_cast<float4*>(x)[i] = r;
}

// ---------------- LayerNorm: fp32 in -> bf16 out ----------------
__global__ __launch_bounds__(256) void ln_k(const float* __restrict__ x,
                                            const float* __restrict__ g,
                                            const float* __restrict__ b,
                                            bf16* __restrict__ out) {
    int row = blockIdx.x;
    int tid = threadIdx.x;
    const float* xr = x + (size_t)row * DD;
    float v0 = xr[tid], v1 = xr[tid + 256], v2 = xr[tid + 512];
    float s = v0 + v1 + v2;
    float ss = v0*v0 + v1*v1 + v2*v2;
    #pragma unroll
    for (int d = 1; d < 64; d <<= 1) { s += __shfl_xor(s, d, 64); ss += __shfl_xor(ss, d, 64); }
    __shared__ float sh[8];
    int w = tid >> 6;
    if ((tid & 63) == 0) { sh[w] = s; sh[4 + w] = ss; }
    __syncthreads();
    s  = sh[0] + sh[1] + sh[2] + sh[3];
    ss = sh[4] + sh[5] + sh[6] + sh[7];
    float mean = s * (1.0f / DD);
    float var  = ss * (1.0f / DD) - mean * mean;
    float rstd = rsqrtf(var + 1e-5f);
    bf16* orow = out + (size_t)row * DD;
    orow[tid]       = __float2bfloat16((v0 - mean) * rstd * g[tid]       + b[tid]);
    orow[tid + 256] = __float2bfloat16((v1 - mean) * rstd * g[tid + 256] + b[tid + 256]);
    orow[tid + 512] = __float2bfloat16((v2 - mean) * rstd * g[tid + 512] + b[tid + 512]);
}

// ================= 256x256 8-phase GEMM (lm-head) =================
// SWZMODE 1: XCD x gets chunk f in [x*250,(x+1)*250); by=f/125, bx=f%125 col-fastest.
// EPI 0 epilogue: LDS-transpose -> one 1KB contiguous NONTEMPORAL dwordx4 store per
// row (d_out is never re-read; keeping it out of L2/L3 preserves W residency).
template<int EPI, int SWZMODE>
__global__ __launch_bounds__(512, 1) void gemm256(
    const bf16* __restrict__ A, const bf16* __restrict__ W,
    const float* __restrict__ bias, const float* __restrict__ resid,
    void* __restrict__ outp, int O, int K, int nwgx)
{
    __shared__ bf16 smem_bf[65536];   // 128 KiB
    char* smem = (char*)smem_bf;
    const int tid = threadIdx.x, lane = tid & 63, wid = tid >> 6;
    const int wm = wid >> 2, wn = wid & 3;
    int f = blockIdx.x;
    if (SWZMODE == 1) { int x = f & 7, r = f >> 3; f = x * ((int)gridDim.x >> 3) + r; }
    const int by = f / nwgx;
    const int bx = f - by * nwgx;
    const int rowBase = by * 256, colBase = bx * 256;
    const int rr = lane & 15, s4 = lane >> 4;
    const int swz = (rr >> 1) & 3;
    const int aOff = (wm * 128 + rr) * 64 + ((s4 ^ swz) << 4);
    const int bOff = (wn * 64 + rr) * 64 + ((s4 ^ swz) << 4);
    const int st_r = (wid << 4) + (lane >> 2);
    const int st_j = lane & 3;
    const bf16* Asrc = A + (size_t)rowBase * K;
    const bf16* Wsrc = W + (size_t)colBase * K;
    const int nk = K >> 6;

    auto STAGE = [&](const bf16* src, int mat, int kt, int kk) {
        char* base = smem + ((kt & 1) << 16) + (mat << 15) + (kk << 14);
        #pragma unroll
        for (int L = 0; L < 2; ++L) {
            int r = (L << 7) + st_r;
            int gs = st_j ^ ((r >> 1) & 3);
            gload16(src + (size_t)r * K + (kt << 6) + (kk << 5) + (gs << 3),
                    (bf16*)(base + (L << 13) + (wid << 10)));
        }
    };

    f32x4 acc[8][4];
    #pragma unroll
    for (int m = 0; m < 8; ++m)
        #pragma unroll
        for (int n = 0; n < 4; ++n) acc[m][n] = (f32x4){0.f, 0.f, 0.f, 0.f};

    STAGE(Asrc, 0, 0, 0); STAGE(Wsrc, 1, 0, 0); STAGE(Asrc, 0, 0, 1); STAGE(Wsrc, 1, 0, 1);
    STAGE(Asrc, 0, 1, 0); STAGE(Wsrc, 1, 1, 0); STAGE(Asrc, 0, 1, 1);
    asm volatile("s_waitcnt vmcnt(6)" ::: "memory");
    __builtin_amdgcn_s_barrier();

    bf16x8 af[8], bfr[2];
    for (int kt = 0; kt < nk; ++kt) {
        char* Ab = smem + ((kt & 1) << 16);
        char* Bb = Ab + 32768;
        #pragma unroll
        for (int q = 0; q < 4; ++q) {
            const int kk = q >> 1, nh = q & 1;
            if (nh == 0) {
                #pragma unroll
                for (int m = 0; m < 8; ++m)
                    af[m] = *reinterpret_cast<const bf16x8*>(Ab + (kk << 14) + aOff + (m << 10));
            }
            bfr[0] = *reinterpret_cast<const bf16x8*>(Bb + (kk << 14) + bOff + ((nh * 2 + 0) << 10));
            bfr[1] = *reinterpret_cast<const bf16x8*>(Bb + (kk << 14) + bOff + ((nh * 2 + 1) << 10));
            if (q == 0) { if (kt + 1 < nk) STAGE(Wsrc, 1, kt + 1, 1); }
            else if (q == 1) { if (kt + 2 < nk) STAGE(Asrc, 0, kt + 2, 0); }
            else if (q == 2) { if (kt + 2 < nk) STAGE(Wsrc, 1, kt + 2, 0); }
            else { if (kt + 2 < nk) STAGE(Asrc, 0, kt + 2, 1); }
            __builtin_amdgcn_s_barrier();
            __builtin_amdgcn_s_setprio(1);
            #pragma unroll
            for (int m = 0; m < 8; ++m) {
                acc[m][nh * 2 + 0] = __builtin_amdgcn_mfma_f32_16x16x32_bf16(af[m], bfr[0], acc[m][nh * 2 + 0], 0, 0, 0);
                acc[m][nh * 2 + 1] = __builtin_amdgcn_mfma_f32_16x16x32_bf16(af[m], bfr[1], acc[m][nh * 2 + 1], 0, 0, 0);
            }
            __builtin_amdgcn_s_setprio(0);
            if (q == 3) {
                if (kt == nk - 2) asm volatile("s_waitcnt vmcnt(0)" ::: "memory");
                else              asm volatile("s_waitcnt vmcnt(6)" ::: "memory");
            }
            __builtin_amdgcn_s_barrier();
        }
    }

    if (EPI == 0) {
        float* outf = reinterpret_cast<float*>(outp);
        float* regf = reinterpret_cast<float*>(smem + wid * 4352);   // [16][68] f32
        #pragma unroll
        for (int m = 0; m < 8; ++m) {
            __syncthreads();
            #pragma unroll
            for (int n = 0; n < 4; ++n)
                #pragma unroll
                for (int j2 = 0; j2 < 4; ++j2)
                    regf[(s4 * 4 + j2) * 68 + n * 16 + rr] = acc[m][n][j2];
            __syncthreads();
            #pragma unroll
            for (int i = 0; i < 4; ++i) {
                int fr = wid + i * 8;
                int srcwid = (fr >> 4) * 4 + (lane >> 4);
                f32x4 v = *reinterpret_cast<const f32x4*>(
                    smem + srcwid * 4352 + (fr & 15) * 272 + (lane & 15) * 16);
                int grow = rowBase + (fr >> 4) * 128 + m * 16 + (fr & 15);
                __builtin_nontemporal_store(v,
                    reinterpret_cast<f32x4*>(&outf[(size_t)grow * O + colBase + lane * 4]));
            }
        }
        return;
    }

    #pragma unroll
    for (int m = 0; m < 8; ++m) {
        int row = rowBase + wm * 128 + m * 16 + s4 * 4;
        #pragma unroll
        for (int n = 0; n < 4; ++n) {
            int col = colBase + wn * 64 + n * 16 + rr;
            float bv = bias ? bias[col] : 0.f;
            #pragma unroll
            for (int j2 = 0; j2 < 4; ++j2) {
                float v = acc[m][n][j2] + bv;
                size_t oi = (size_t)(row + j2) * O + col;
                if (EPI == 1) v += resid[oi];
                if (EPI == 3) reinterpret_cast<bf16*>(outp)[oi] = __float2bfloat16(v);
                else          reinterpret_cast<float*>(outp)[oi] = v;
            }
        }
    }
}

// ================= 256x128 GEMM (qkv / fc): 4 waves, wave tile 128x64 =================
// 32 MFMA per wave per K-step (2x the 128^2 tile's staging amortization).
// EPI 2: bf16 + bias + gelu    EPI 3: bf16 + bias
template<int EPI>
__global__ __launch_bounds__(256) void gemm_big(
    const bf16* __restrict__ A, const bf16* __restrict__ W,
    const float* __restrict__ bias, void* __restrict__ outp, int O, int K)
{
    __shared__ bf16 As[256 * 32];
    __shared__ bf16 Bs[128 * 32];
    const int tid = threadIdx.x;
    const int lane = tid & 63;
    const int w = tid >> 6;
    const int wm = w >> 1, wn = w & 1;
    const int rowBase = blockIdx.y * 256, colBase = blockIdx.x * 128;

    const int rr = lane & 15, kq = (lane >> 4) * 8;
    const int srow = lane >> 2;
    const int scol = (lane & 3) * 8;

    f32x4 acc[8][4];
    #pragma unroll
    for (int m = 0; m < 8; ++m)
        #pragma unroll
        for (int n = 0; n < 4; ++n) acc[m][n] = (f32x4){0.f, 0.f, 0.f, 0.f};

    for (int k0 = 0; k0 < K; k0 += 32) {
        #pragma unroll
        for (int p = 0; p < 4; ++p) {       // A: 16 stripes of 16 rows
            int s = (w + p * 4) * 16;
            gload16(&A[(size_t)(rowBase + s + srow) * K + k0 + scol], &As[s * 32]);
        }
        #pragma unroll
        for (int p = 0; p < 2; ++p) {       // B: 8 stripes
            int s = (w + p * 4) * 16;
            gload16(&W[(size_t)(colBase + s + srow) * K + k0 + scol], &Bs[s * 32]);
        }
        __syncthreads();
        bf16x8 b[4];
        #pragma unroll
        for (int n = 0; n < 4; ++n)
            b[n] = *reinterpret_cast<const bf16x8*>(&Bs[(wn * 64 + n * 16 + rr) * 32 + kq]);
        #pragma unroll
        for (int m = 0; m < 8; ++m) {
            bf16x8 a = *reinterpret_cast<const bf16x8*>(&As[(wm * 128 + m * 16 + rr) * 32 + kq]);
            #pragma unroll
            for (int n = 0; n < 4; ++n)
                acc[m][n] = __builtin_amdgcn_mfma_f32_16x16x32_bf16(a, b[n], acc[m][n], 0, 0, 0);
        }
        __syncthreads();
    }

    #pragma unroll
    for (int m = 0; m < 8; ++m) {
        int row = rowBase + wm * 128 + m * 16 + (lane >> 4) * 4;
        #pragma unroll
        for (int n = 0; n < 4; ++n) {
            int col = colBase + wn * 64 + n * 16 + (lane & 15);
            float bv = bias[col];
            #pragma unroll
            for (int j2 = 0; j2 < 4; ++j2) {
                float v = acc[m][n][j2] + bv;
                if (EPI == 2) v = 0.5f * v * (1.0f + erff(v * 0.70710678118654752f));
                reinterpret_cast<bf16*>(outp)[(size_t)(row + j2) * O + col] = __float2bfloat16(v);
            }
        }
    }
}

// ---------------- GEMM 128xBN (m97 structure): proj / fc2 ----------------
// BN=64: wave tile 64x32 (acc[4][2]) -> 2x grid for N=768 shapes to cover all CUs.
// EPI 1: f32 + bias + residual
template<int EPI, int BN>
__global__ __launch_bounds__(256) void gemm_bt(
    const bf16* __restrict__ A, const bf16* __restrict__ W,
    const float* __restrict__ bias, const float* __restrict__ resid,
    void* __restrict__ outp, int O, int K)
{
    constexpr int NF = BN / 32;          // n-fragments per wave (4 or 2)
    __shared__ bf16 As[128 * 32];
    __shared__ bf16 Bs[BN * 32];
    const int tid = threadIdx.x;
    const int lane = tid & 63;
    const int w = tid >> 6;
    const int wm = w >> 1, wn = w & 1;
    const int rowBase = blockIdx.y * 128, colBase = blockIdx.x * BN;

    const int rr = lane & 15, kq = (lane >> 4) * 8;
    const int srow = lane >> 2;
    const int scol = (lane & 3) * 8;

    f32x4 acc[4][NF];
    #pragma unroll
    for (int m = 0; m < 4; ++m)
        #pragma unroll
        for (int n = 0; n < NF; ++n) acc[m][n] = (f32x4){0.f, 0.f, 0.f, 0.f};

    for (int k0 = 0; k0 < K; k0 += 32) {
        #pragma unroll
        for (int p = 0; p < 2; ++p) {
            int s = w * 16 + p * 64;
            gload16(&A[(size_t)(rowBase + s + srow) * K + k0 + scol], &As[s * 32]);
        }
        #pragma unroll
        for (int p = 0; p < BN / 64; ++p) {
            int s = w * 16 + p * 64;
            gload16(&W[(size_t)(colBase + s + srow) * K + k0 + scol], &Bs[s * 32]);
        }
        __syncthreads();
        bf16x8 a[4], b[NF];
        #pragma unroll
        for (int m = 0; m < 4; ++m)
            a[m] = *reinterpret_cast<const bf16x8*>(&As[(wm * 64 + m * 16 + rr) * 32 + kq]);
        #pragma unroll
        for (int n = 0; n < NF; ++n)
            b[n] = *reinterpret_cast<const bf16x8*>(&Bs[(wn * (BN/2) + n * 16 + rr) * 32 + kq]);
        #pragma unroll
        for (int m = 0; m < 4; ++m)
            #pragma unroll
            for (int n = 0; n < NF; ++n)
                acc[m][n] = __builtin_amdgcn_mfma_f32_16x16x32_bf16(a[m], b[n], acc[m][n], 0, 0, 0);
        __syncthreads();
    }

    #pragma unroll
    for (int m = 0; m < 4; ++m) {
        int row = rowBase + wm * 64 + m * 16 + (lane >> 4) * 4;
        #pragma unroll
        for (int n = 0; n < NF; ++n) {
            int col = colBase + wn * (BN/2) + n * 16 + (lane & 15);
            float bv = bias ? bias[col] : 0.f;
            #pragma unroll
            for (int j2 = 0; j2 < 4; ++j2) {
                float v = acc[m][n][j2] + bv;
                size_t oi = (size_t)(row + j2) * O + col;
                if (EPI == 1) v += resid[oi];
                reinterpret_cast<float*>(outp)[oi] = v;
            }
        }
    }
}

// ---------------- flash attention (R2/R6-proven version) ----------------
__global__ __launch_bounds__(256, 2) void attn_flash(const bf16* __restrict__ qkvb,
                                                     bf16* __restrict__ ybf)
{
    __shared__ bf16 Qs[128][72];   // Q tile; reused as P (wave w owns rows [w*32, w*32+32))
    __shared__ bf16 Ks[64][72];    // K tile  [j][d]
    __shared__ bf16 Vt[64][72];    // V tile transposed [d][j]

    const int tid = threadIdx.x, lane = tid & 63, w = tid >> 6;
    const int qi = 15 - (blockIdx.x / 24);          // big-work tiles first
    const int bh = blockIdx.x % 24;
    const int b = bh / HH, h = bh % HH;
    const int qbase = qi * 128;
    const int rr = lane & 15, g8 = (lane >> 4) * 8, g4 = (lane >> 4) * 4;

    {
        int seg = tid & 7, jr = tid >> 3;
        #pragma unroll
        for (int p = 0; p < 4; ++p) {
            int q = jr + p * 32;
            *reinterpret_cast<uint4*>(&Qs[q][seg * 8]) =
                *reinterpret_cast<const uint4*>(&qkvb[(size_t)(b*TT + qbase + q) * 2304 + h*64 + seg*8]);
        }
    }
    __syncthreads();

    bf16x8 qf[2][2];
    #pragma unroll
    for (int m = 0; m < 2; ++m)
        #pragma unroll
        for (int c = 0; c < 2; ++c)
            qf[m][c] = *reinterpret_cast<const bf16x8*>(&Qs[w*32 + m*16 + rr][c*32 + g8]);

    float mst[2][4], lst[2][4];
    f32x4 o[2][4];
    #pragma unroll
    for (int m = 0; m < 2; ++m)
        #pragma unroll
        for (int jj = 0; jj < 4; ++jj) { mst[m][jj] = -1e30f; lst[m][jj] = 0.f; }
    #pragma unroll
    for (int m = 0; m < 2; ++m)
        #pragma unroll
        for (int nd = 0; nd < 4; ++nd) o[m][nd] = (f32x4){0.f,0.f,0.f,0.f};

    const int ktmax = 2 * qi + 2;
    for (int kt = 0; kt < ktmax; ++kt) {
        __syncthreads();
        {
            int seg = tid & 7, jr = tid >> 3;
            #pragma unroll
            for (int p = 0; p < 2; ++p) {
                int j = jr + p * 32;
                *reinterpret_cast<uint4*>(&Ks[j][seg * 8]) =
                    *reinterpret_cast<const uint4*>(&qkvb[(size_t)(b*TT + kt*64 + j) * 2304 + DD + h*64 + seg*8]);
            }
            int jv = tid & 31, d0 = (tid >> 5) * 8;
            #pragma unroll
            for (int p = 0; p < 2; ++p) {
                int j = jv + p * 32;
                uint4 raw = *reinterpret_cast<const uint4*>(&qkvb[(size_t)(b*TT + kt*64 + j) * 2304 + 2*DD + h*64 + d0]);
                const bf16* vv = reinterpret_cast<const bf16*>(&raw);
                #pragma unroll
                for (int i2 = 0; i2 < 8; ++i2) Vt[d0 + i2][j] = vv[i2];
            }
        }
        __syncthreads();

        bf16x8 kf[4][2];
        #pragma unroll
        for (int n = 0; n < 4; ++n)
            #pragma unroll
            for (int c = 0; c < 2; ++c)
                kf[n][c] = *reinterpret_cast<const bf16x8*>(&Ks[n*16 + rr][c*32 + g8]);
        f32x4 sacc[2][4];
        #pragma unroll
        for (int m = 0; m < 2; ++m)
            #pragma unroll
            for (int n = 0; n < 4; ++n) sacc[m][n] = (f32x4){0.f,0.f,0.f,0.f};
        #pragma unroll
        for (int m = 0; m < 2; ++m)
            #pragma unroll
            for (int n = 0; n < 4; ++n)
                #pragma unroll
                for (int c = 0; c < 2; ++c)
                    sacc[m][n] = __builtin_amdgcn_mfma_f32_16x16x32_bf16(qf[m][c], kf[n][c], sacc[m][n], 0, 0, 0);

        float corr[2][4];
        #pragma unroll
        for (int m = 0; m < 2; ++m) {
            #pragma unroll
            for (int jj = 0; jj < 4; ++jj) {
                const int qg = qbase + w*32 + m*16 + g4 + jj;
                float pm = -1e30f;
                #pragma unroll
                for (int n = 0; n < 4; ++n) {
                    float v = sacc[m][n][jj] * 0.125f;
                    int jg = kt*64 + n*16 + rr;
                    v = (jg <= qg) ? v : -1e30f;
                    sacc[m][n][jj] = v;
                    pm = fmaxf(pm, v);
                }
                pm = fmaxf(pm, __shfl_xor(pm, 1, 64));
                pm = fmaxf(pm, __shfl_xor(pm, 2, 64));
                pm = fmaxf(pm, __shfl_xor(pm, 4, 64));
                pm = fmaxf(pm, __shfl_xor(pm, 8, 64));
                float nm = fmaxf(mst[m][jj], pm);
                float cv = __expf(mst[m][jj] - nm);
                float r = 0.f;
                #pragma unroll
                for (int n = 0; n < 4; ++n) {
                    float p = __expf(sacc[m][n][jj] - nm);
                    r += p;
                    Qs[w*32 + m*16 + g4 + jj][n*16 + rr] = __float2bfloat16(p);
                }
                r += __shfl_xor(r, 1, 64);
                r += __shfl_xor(r, 2, 64);
                r += __shfl_xor(r, 4, 64);
                r += __shfl_xor(r, 8, 64);
                lst[m][jj] = lst[m][jj] * cv + r;
                mst[m][jj] = nm;
                corr[m][jj] = cv;
            }
        }
        #pragma unroll
        for (int m = 0; m < 2; ++m)
            #pragma unroll
            for (int nd = 0; nd < 4; ++nd)
                #pragma unroll
                for (int jj = 0; jj < 4; ++jj) o[m][nd][jj] *= corr[m][jj];

        __builtin_amdgcn_sched_barrier(0);

        bf16x8 pf[2][2], vf[4][2];
        #pragma unroll
        for (int m = 0; m < 2; ++m)
            #pragma unroll
            for (int c = 0; c < 2; ++c)
                pf[m][c] = *reinterpret_cast<const bf16x8*>(&Qs[w*32 + m*16 + rr][c*32 + g8]);
        #pragma unroll
        for (int nd = 0; nd < 4; ++nd)
            #pragma unroll
            for (int c = 0; c < 2; ++c)
                vf[nd][c] = *reinterpret_cast<const bf16x8*>(&Vt[nd*16 + rr][c*32 + g8]);
        #pragma unroll
        for (int m = 0; m < 2; ++m)
            #pragma unroll
            for (int nd = 0; nd < 4; ++nd)
                #pragma unroll
                for (int c = 0; c < 2; ++c)
                    o[m][nd] = __builtin_amdgcn_mfma_f32_16x16x32_bf16(pf[m][c], vf[nd][c], o[m][nd], 0, 0, 0);
    }

    #pragma unroll
    for (int m = 0; m < 2; ++m) {
        #pragma unroll
        for (int jj = 0; jj < 4; ++jj) {
            const int qg = qbase + w*32 + m*16 + g4 + jj;
            const float inv = 1.0f / lst[m][jj];
            #pragma unroll
            for (int nd = 0; nd < 4; ++nd)
                ybf[(size_t)(b*TT + qg) * DD + h*64 + nd*16 + rr] =
                    __float2bfloat16(o[m][nd][jj] * inv);
        }
    }
}

// ---------------- host ----------------
extern "C" void kernel_launch(void* const* d_in, const int* in_sizes, int n_in,
                              void* d_out, int out_size, void* d_ws, size_t ws_size,
                              hipStream_t stream) {
    const int*   idx    = (const int*)  d_in[0];
    const float* wte    = (const float*)d_in[1];
    const float* wpe    = (const float*)d_in[2];
    const float* ln1_g  = (const float*)d_in[3];
    const float* ln1_b  = (const float*)d_in[4];
    const float* qkv_w  = (const float*)d_in[5];
    const float* qkv_b  = (const float*)d_in[6];
    const float* proj_w = (const float*)d_in[7];
    const float* proj_b = (const float*)d_in[8];
    const float* ln2_g  = (const float*)d_in[9];
    const float* ln2_b  = (const float*)d_in[10];
    const float* fc_w   = (const float*)d_in[11];
    const float* fc_b   = (const float*)d_in[12];
    const float* fc2_w  = (const float*)d_in[13];
    const float* fc2_b  = (const float*)d_in[14];
    const float* lnf_g  = (const float*)d_in[15];
    const float* lnf_b  = (const float*)d_in[16];

    char* ws = (char*)d_ws;
    size_t off = 0;
    auto alloc = [&](size_t bytes) -> void* {
        void* p = ws + off;
        off += (bytes + 255) & ~(size_t)255;
        return p;
    };
    float* x     = (float*)alloc((size_t)NTOK * DD * 4);
    bf16*  qkvb  = (bf16*) alloc((size_t)NTOK * 3 * DD * 2);
    bf16*  lnb   = (bf16*) alloc((size_t)NTOK * DD * 2);
    bf16*  ybf   = (bf16*) alloc((size_t)NTOK * DD * 2);
    bf16*  ffb   = (bf16*) alloc((size_t)NTOK * 4 * DD * 2);
    bf16*  w_qkv = (bf16*) alloc((size_t)NL * 3 * DD * DD * 2);
    bf16*  w_prj = (bf16*) alloc((size_t)NL * DD * DD * 2);
    bf16*  w_fc  = (bf16*) alloc((size_t)NL * 4 * DD * DD * 2);
    bf16*  w_fc2 = (bf16*) alloc((size_t)NL * DD * 4 * DD * 2);
    bf16*  w_wte = (bf16*) alloc((size_t)VV * DD * 2);

    // one fused cast dispatch for all weights
    {
        constexpr int totalBlocks = (VV*DD/4 + NL*3*DD*DD/4 + NL*DD*DD/4 +
                                     NL*4*DD*DD/4 + NL*DD*4*DD/4) / 256;
        cast_all<<<dim3(totalBlocks), dim3(256), 0, stream>>>(
            wte, qkv_w, proj_w, fc_w, fc2_w, w_wte, w_qkv, w_prj, w_fc, w_fc2);
    }

    embed_k<<<dim3(NTOK * (DD/4) / 256), dim3(256), 0, stream>>>(idx, wte, wpe, x);

    for (int l = 0; l < NL; ++l) {
        ln_k<<<dim3(NTOK), dim3(256), 0, stream>>>(x, ln1_g + l * DD, ln1_b + l * DD, lnb);
        gemm_big<3><<<dim3(3 * DD / 128, NTOK / 256), dim3(256), 0, stream>>>(
            lnb, w_qkv + (size_t)l * 3 * DD * DD, qkv_b + l * 3 * DD,
            (void*)qkvb, 3 * DD, DD);
        attn_flash<<<dim3(24 * (TT / 128)), dim3(256), 0, stream>>>(qkvb, ybf);
        gemm_bt<1,64><<<dim3(DD / 64, 32), dim3(256), 0, stream>>>(
            ybf, w_prj + (size_t)l * DD * DD, proj_b + l * DD, x,
            (void*)x, DD, DD);
        ln_k<<<dim3(NTOK), dim3(256), 0, stream>>>(x, ln2_g + l * DD, ln2_b + l * DD, lnb);
        gemm_big<2><<<dim3(4 * DD / 128, NTOK / 256), dim3(256), 0, stream>>>(
            lnb, w_fc + (size_t)l * 4 * DD * DD, fc_b + l * 4 * DD,
            (void*)ffb, 4 * DD, DD);
        gemm_bt<1,64><<<dim3(DD / 64, 32), dim3(256), 0, stream>>>(
            ffb, w_fc2 + (size_t)l * DD * 4 * DD, fc2_b + l * DD, x,
            (void*)x, DD, 4 * DD);
    }

    ln_k<<<dim3(NTOK), dim3(256), 0, stream>>>(x, lnf_g, lnf_b, lnb);
    gemm256<0, 1><<<dim3((VV / 256) * (NTOK / 256)), dim3(512), 0, stream>>>(
        lnb, w_wte, nullptr, nullptr, d_out, VV, DD, VV / 256);
}

// Round 14
// 799.899 us; speedup vs baseline: 1.3015x; 1.3015x over previous
//
#include <hip/hip_runtime.h>
#include <hip/hip_bf16.h>
#include <math.h>

#define BB 2
#define TT 2048
#define DD 768
#define HH 12
#define NTOK (BB*TT)   // 4096
#define VV 32000
#define NL 2

typedef __hip_bfloat16 bf16;
typedef __attribute__((ext_vector_type(8))) short bf16x8;
typedef __attribute__((ext_vector_type(4))) float f32x4;

typedef const __attribute__((address_space(1))) unsigned int* gas_u32;
typedef __attribute__((address_space(3))) unsigned int* las_u32;

__device__ __forceinline__ void gload16(const bf16* g, bf16* l) {
    __builtin_amdgcn_global_load_lds((gas_u32)g, (las_u32)l, 16, 0, 0);
}
__device__ __forceinline__ unsigned short f2bu(float f) {
    bf16 h = __float2bfloat16(f);
    return *reinterpret_cast<unsigned short*>(&h);
}

// ---------------- fused fp32 -> bf16 cast of ALL weights (one dispatch) ----------------
__global__ __launch_bounds__(256) void cast_all(
    const float* __restrict__ wte, const float* __restrict__ qkv_w,
    const float* __restrict__ proj_w, const float* __restrict__ fc_w,
    const float* __restrict__ fc2_w,
    bf16* __restrict__ o_wte, bf16* __restrict__ o_qkv, bf16* __restrict__ o_prj,
    bf16* __restrict__ o_fc, bf16* __restrict__ o_fc2)
{
    constexpr int N_WTE = VV * DD / 4;
    constexpr int N_QKV = NL * 3 * DD * DD / 4;
    constexpr int N_PRJ = NL * DD * DD / 4;
    constexpr int N_FC  = NL * 4 * DD * DD / 4;
    int g = blockIdx.x * 256 + threadIdx.x;
    const float* s; bf16* d;
    if (g < N_WTE) { s = wte; d = o_wte; }
    else if ((g -= N_WTE) < N_QKV) { s = qkv_w; d = o_qkv; }
    else if ((g -= N_QKV) < N_PRJ) { s = proj_w; d = o_prj; }
    else if ((g -= N_PRJ) < N_FC)  { s = fc_w;  d = o_fc; }
    else { g -= N_FC; s = fc2_w; d = o_fc2; }
    float4 v = reinterpret_cast<const float4*>(s)[g];
    ushort4 r;
    r.x = f2bu(v.x);
    r.y = f2bu(v.y);
    r.z = f2bu(v.z);
    r.w = f2bu(v.w);
    reinterpret_cast<ushort4*>(d)[g] = r;
}

// ---------------- embedding: x = wte[idx] + wpe[t] ----------------
__global__ void embed_k(const int* __restrict__ idx, const float* __restrict__ wte,
                        const float* __restrict__ wpe, float* __restrict__ x) {
    int i = blockIdx.x * 256 + threadIdx.x;          // over NTOK * (DD/4)
    int n = i / (DD/4), d4 = i - n * (DD/4);
    int tok = idx[n];
    int t = n & (TT - 1);
    float4 a = reinterpret_cast<const float4*>(wte + (size_t)tok * DD)[d4];
    float4 p = reinterpret_cast<const float4*>(wpe + (size_t)t * DD)[d4];
    float4 r; r.x = a.x+p.x; r.y = a.y+p.y; r.z = a.z+p.z; r.w = a.w+p.w;
    reinterpret_cast<float4*>(x)[i] = r;
}

// ---------------- LayerNorm: fp32 in -> bf16 out ----------------
__global__ __launch_bounds__(256) void ln_k(const float* __restrict__ x,
                                            const float* __restrict__ g,
                                            const float* __restrict__ b,
                                            bf16* __restrict__ out) {
    int row = blockIdx.x;
    int tid = threadIdx.x;
    const float* xr = x + (size_t)row * DD;
    float v0 = xr[tid], v1 = xr[tid + 256], v2 = xr[tid + 512];
    float s = v0 + v1 + v2;
    float ss = v0*v0 + v1*v1 + v2*v2;
    #pragma unroll
    for (int d = 1; d < 64; d <<= 1) { s += __shfl_xor(s, d, 64); ss += __shfl_xor(ss, d, 64); }
    __shared__ float sh[8];
    int w = tid >> 6;
    if ((tid & 63) == 0) { sh[w] = s; sh[4 + w] = ss; }
    __syncthreads();
    s  = sh[0] + sh[1] + sh[2] + sh[3];
    ss = sh[4] + sh[5] + sh[6] + sh[7];
    float mean = s * (1.0f / DD);
    float var  = ss * (1.0f / DD) - mean * mean;
    float rstd = rsqrtf(var + 1e-5f);
    bf16* orow = out + (size_t)row * DD;
    orow[tid]       = __float2bfloat16((v0 - mean) * rstd * g[tid]       + b[tid]);
    orow[tid + 256] = __float2bfloat16((v1 - mean) * rstd * g[tid + 256] + b[tid + 256]);
    orow[tid + 512] = __float2bfloat16((v2 - mean) * rstd * g[tid + 512] + b[tid + 512]);
}

// ================= 256x256 8-phase GEMM (lm-head) =================
// SWZMODE 1: XCD x gets chunk f in [x*250,(x+1)*250); by=f/125, bx=f%125 col-fastest.
// EPI 0 epilogue: LDS-transpose -> one 1KB contiguous NONTEMPORAL dwordx4 store per
// row (d_out is never re-read; keeping it out of L2/L3 preserves W residency).
template<int EPI, int SWZMODE>
__global__ __launch_bounds__(512, 1) void gemm256(
    const bf16* __restrict__ A, const bf16* __restrict__ W,
    const float* __restrict__ bias, const float* __restrict__ resid,
    void* __restrict__ outp, int O, int K, int nwgx)
{
    __shared__ bf16 smem_bf[65536];   // 128 KiB
    char* smem = (char*)smem_bf;
    const int tid = threadIdx.x, lane = tid & 63, wid = tid >> 6;
    const int wm = wid >> 2, wn = wid & 3;
    int f = blockIdx.x;
    if (SWZMODE == 1) { int x = f & 7, r = f >> 3; f = x * ((int)gridDim.x >> 3) + r; }
    const int by = f / nwgx;
    const int bx = f - by * nwgx;
    const int rowBase = by * 256, colBase = bx * 256;
    const int rr = lane & 15, s4 = lane >> 4;
    const int swz = (rr >> 1) & 3;
    const int aOff = (wm * 128 + rr) * 64 + ((s4 ^ swz) << 4);
    const int bOff = (wn * 64 + rr) * 64 + ((s4 ^ swz) << 4);
    const int st_r = (wid << 4) + (lane >> 2);
    const int st_j = lane & 3;
    const bf16* Asrc = A + (size_t)rowBase * K;
    const bf16* Wsrc = W + (size_t)colBase * K;
    const int nk = K >> 6;

    auto STAGE = [&](const bf16* src, int mat, int kt, int kk) {
        char* base = smem + ((kt & 1) << 16) + (mat << 15) + (kk << 14);
        #pragma unroll
        for (int L = 0; L < 2; ++L) {
            int r = (L << 7) + st_r;
            int gs = st_j ^ ((r >> 1) & 3);
            gload16(src + (size_t)r * K + (kt << 6) + (kk << 5) + (gs << 3),
                    (bf16*)(base + (L << 13) + (wid << 10)));
        }
    };

    f32x4 acc[8][4];
    #pragma unroll
    for (int m = 0; m < 8; ++m)
        #pragma unroll
        for (int n = 0; n < 4; ++n) acc[m][n] = (f32x4){0.f, 0.f, 0.f, 0.f};

    STAGE(Asrc, 0, 0, 0); STAGE(Wsrc, 1, 0, 0); STAGE(Asrc, 0, 0, 1); STAGE(Wsrc, 1, 0, 1);
    STAGE(Asrc, 0, 1, 0); STAGE(Wsrc, 1, 1, 0); STAGE(Asrc, 0, 1, 1);
    asm volatile("s_waitcnt vmcnt(6)" ::: "memory");
    __builtin_amdgcn_s_barrier();

    bf16x8 af[8], bfr[2];
    for (int kt = 0; kt < nk; ++kt) {
        char* Ab = smem + ((kt & 1) << 16);
        char* Bb = Ab + 32768;
        #pragma unroll
        for (int q = 0; q < 4; ++q) {
            const int kk = q >> 1, nh = q & 1;
            if (nh == 0) {
                #pragma unroll
                for (int m = 0; m < 8; ++m)
                    af[m] = *reinterpret_cast<const bf16x8*>(Ab + (kk << 14) + aOff + (m << 10));
            }
            bfr[0] = *reinterpret_cast<const bf16x8*>(Bb + (kk << 14) + bOff + ((nh * 2 + 0) << 10));
            bfr[1] = *reinterpret_cast<const bf16x8*>(Bb + (kk << 14) + bOff + ((nh * 2 + 1) << 10));
            if (q == 0) { if (kt + 1 < nk) STAGE(Wsrc, 1, kt + 1, 1); }
            else if (q == 1) { if (kt + 2 < nk) STAGE(Asrc, 0, kt + 2, 0); }
            else if (q == 2) { if (kt + 2 < nk) STAGE(Wsrc, 1, kt + 2, 0); }
            else { if (kt + 2 < nk) STAGE(Asrc, 0, kt + 2, 1); }
            __builtin_amdgcn_s_barrier();
            __builtin_amdgcn_s_setprio(1);
            #pragma unroll
            for (int m = 0; m < 8; ++m) {
                acc[m][nh * 2 + 0] = __builtin_amdgcn_mfma_f32_16x16x32_bf16(af[m], bfr[0], acc[m][nh * 2 + 0], 0, 0, 0);
                acc[m][nh * 2 + 1] = __builtin_amdgcn_mfma_f32_16x16x32_bf16(af[m], bfr[1], acc[m][nh * 2 + 1], 0, 0, 0);
            }
            __builtin_amdgcn_s_setprio(0);
            if (q == 3) {
                if (kt == nk - 2) asm volatile("s_waitcnt vmcnt(0)" ::: "memory");
                else              asm volatile("s_waitcnt vmcnt(6)" ::: "memory");
            }
            __builtin_amdgcn_s_barrier();
        }
    }

    if (EPI == 0) {
        float* outf = reinterpret_cast<float*>(outp);
        float* regf = reinterpret_cast<float*>(smem + wid * 4352);   // [16][68] f32
        #pragma unroll
        for (int m = 0; m < 8; ++m) {
            __syncthreads();
            #pragma unroll
            for (int n = 0; n < 4; ++n)
                #pragma unroll
                for (int j2 = 0; j2 < 4; ++j2)
                    regf[(s4 * 4 + j2) * 68 + n * 16 + rr] = acc[m][n][j2];
            __syncthreads();
            #pragma unroll
            for (int i = 0; i < 4; ++i) {
                int fr = wid + i * 8;
                int srcwid = (fr >> 4) * 4 + (lane >> 4);
                f32x4 v = *reinterpret_cast<const f32x4*>(
                    smem + srcwid * 4352 + (fr & 15) * 272 + (lane & 15) * 16);
                int grow = rowBase + (fr >> 4) * 128 + m * 16 + (fr & 15);
                __builtin_nontemporal_store(v,
                    reinterpret_cast<f32x4*>(&outf[(size_t)grow * O + colBase + lane * 4]));
            }
        }
        return;
    }

    #pragma unroll
    for (int m = 0; m < 8; ++m) {
        int row = rowBase + wm * 128 + m * 16 + s4 * 4;
        #pragma unroll
        for (int n = 0; n < 4; ++n) {
            int col = colBase + wn * 64 + n * 16 + rr;
            float bv = bias ? bias[col] : 0.f;
            #pragma unroll
            for (int j2 = 0; j2 < 4; ++j2) {
                float v = acc[m][n][j2] + bv;
                size_t oi = (size_t)(row + j2) * O + col;
                if (EPI == 1) v += resid[oi];
                if (EPI == 3) reinterpret_cast<bf16*>(outp)[oi] = __float2bfloat16(v);
                else          reinterpret_cast<float*>(outp)[oi] = v;
            }
        }
    }
}

// ---------------- GEMM 128xBN (m97 structure): C[n,o] = A[n,:]*W[o,:] ----------------
// BN=128: wave tile 64x64 (acc[4][4]). BN=64: wave tile 64x32 (acc[4][2]) -> 2x grid
// for N=768 shapes (proj/fc2) to cover all CUs.
// EPI 0: f32 (+bias)  1: f32+bias+resid  2: bf16+bias+gelu  3: bf16+bias
template<int EPI, int BN>
__global__ __launch_bounds__(256) void gemm_bt(
    const bf16* __restrict__ A, const bf16* __restrict__ W,
    const float* __restrict__ bias, const float* __restrict__ resid,
    void* __restrict__ outp, int O, int K)
{
    constexpr int NF = BN / 32;          // n-fragments per wave (4 or 2)
    __shared__ bf16 As[128 * 32];
    __shared__ bf16 Bs[BN * 32];
    const int tid = threadIdx.x;
    const int lane = tid & 63;
    const int w = tid >> 6;
    const int wm = w >> 1, wn = w & 1;
    const int rowBase = blockIdx.y * 128, colBase = blockIdx.x * BN;

    const int rr = lane & 15, kq = (lane >> 4) * 8;
    const int srow = lane >> 2;
    const int scol = (lane & 3) * 8;

    f32x4 acc[4][NF];
    #pragma unroll
    for (int m = 0; m < 4; ++m)
        #pragma unroll
        for (int n = 0; n < NF; ++n) acc[m][n] = (f32x4){0.f, 0.f, 0.f, 0.f};

    for (int k0 = 0; k0 < K; k0 += 32) {
        #pragma unroll
        for (int p = 0; p < 2; ++p) {
            int s = w * 16 + p * 64;
            gload16(&A[(size_t)(rowBase + s + srow) * K + k0 + scol], &As[s * 32]);
        }
        #pragma unroll
        for (int p = 0; p < BN / 64; ++p) {
            int s = w * 16 + p * 64;
            gload16(&W[(size_t)(colBase + s + srow) * K + k0 + scol], &Bs[s * 32]);
        }
        __syncthreads();
        bf16x8 a[4], b[NF];
        #pragma unroll
        for (int m = 0; m < 4; ++m)
            a[m] = *reinterpret_cast<const bf16x8*>(&As[(wm * 64 + m * 16 + rr) * 32 + kq]);
        #pragma unroll
        for (int n = 0; n < NF; ++n)
            b[n] = *reinterpret_cast<const bf16x8*>(&Bs[(wn * (BN/2) + n * 16 + rr) * 32 + kq]);
        #pragma unroll
        for (int m = 0; m < 4; ++m)
            #pragma unroll
            for (int n = 0; n < NF; ++n)
                acc[m][n] = __builtin_amdgcn_mfma_f32_16x16x32_bf16(a[m], b[n], acc[m][n], 0, 0, 0);
        __syncthreads();
    }

    #pragma unroll
    for (int m = 0; m < 4; ++m) {
        int row = rowBase + wm * 64 + m * 16 + (lane >> 4) * 4;
        #pragma unroll
        for (int n = 0; n < NF; ++n) {
            int col = colBase + wn * (BN/2) + n * 16 + (lane & 15);
            float bv = bias ? bias[col] : 0.f;
            #pragma unroll
            for (int j2 = 0; j2 < 4; ++j2) {
                float v = acc[m][n][j2] + bv;
                size_t oi = (size_t)(row + j2) * O + col;
                if (EPI == 1) v += resid[oi];
                if (EPI == 2) {
                    v = 0.5f * v * (1.0f + erff(v * 0.70710678118654752f));
                    reinterpret_cast<bf16*>(outp)[oi] = __float2bfloat16(v);
                } else if (EPI == 3) {
                    reinterpret_cast<bf16*>(outp)[oi] = __float2bfloat16(v);
                } else {
                    reinterpret_cast<float*>(outp)[oi] = v;
                }
            }
        }
    }
}

// ---------------- flash attention (R2/R6-proven version) ----------------
__global__ __launch_bounds__(256, 2) void attn_flash(const bf16* __restrict__ qkvb,
                                                     bf16* __restrict__ ybf)
{
    __shared__ bf16 Qs[128][72];   // Q tile; reused as P (wave w owns rows [w*32, w*32+32))
    __shared__ bf16 Ks[64][72];    // K tile  [j][d]
    __shared__ bf16 Vt[64][72];    // V tile transposed [d][j]

    const int tid = threadIdx.x, lane = tid & 63, w = tid >> 6;
    const int qi = 15 - (blockIdx.x / 24);          // big-work tiles first
    const int bh = blockIdx.x % 24;
    const int b = bh / HH, h = bh % HH;
    const int qbase = qi * 128;
    const int rr = lane & 15, g8 = (lane >> 4) * 8, g4 = (lane >> 4) * 4;

    {
        int seg = tid & 7, jr = tid >> 3;
        #pragma unroll
        for (int p = 0; p < 4; ++p) {
            int q = jr + p * 32;
            *reinterpret_cast<uint4*>(&Qs[q][seg * 8]) =
                *reinterpret_cast<const uint4*>(&qkvb[(size_t)(b*TT + qbase + q) * 2304 + h*64 + seg*8]);
        }
    }
    __syncthreads();

    bf16x8 qf[2][2];
    #pragma unroll
    for (int m = 0; m < 2; ++m)
        #pragma unroll
        for (int c = 0; c < 2; ++c)
            qf[m][c] = *reinterpret_cast<const bf16x8*>(&Qs[w*32 + m*16 + rr][c*32 + g8]);

    float mst[2][4], lst[2][4];
    f32x4 o[2][4];
    #pragma unroll
    for (int m = 0; m < 2; ++m)
        #pragma unroll
        for (int jj = 0; jj < 4; ++jj) { mst[m][jj] = -1e30f; lst[m][jj] = 0.f; }
    #pragma unroll
    for (int m = 0; m < 2; ++m)
        #pragma unroll
        for (int nd = 0; nd < 4; ++nd) o[m][nd] = (f32x4){0.f,0.f,0.f,0.f};

    const int ktmax = 2 * qi + 2;
    for (int kt = 0; kt < ktmax; ++kt) {
        __syncthreads();
        {
            int seg = tid & 7, jr = tid >> 3;
            #pragma unroll
            for (int p = 0; p < 2; ++p) {
                int j = jr + p * 32;
                *reinterpret_cast<uint4*>(&Ks[j][seg * 8]) =
                    *reinterpret_cast<const uint4*>(&qkvb[(size_t)(b*TT + kt*64 + j) * 2304 + DD + h*64 + seg*8]);
            }
            int jv = tid & 31, d0 = (tid >> 5) * 8;
            #pragma unroll
            for (int p = 0; p < 2; ++p) {
                int j = jv + p * 32;
                uint4 raw = *reinterpret_cast<const uint4*>(&qkvb[(size_t)(b*TT + kt*64 + j) * 2304 + 2*DD + h*64 + d0]);
                const bf16* vv = reinterpret_cast<const bf16*>(&raw);
                #pragma unroll
                for (int i2 = 0; i2 < 8; ++i2) Vt[d0 + i2][j] = vv[i2];
            }
        }
        __syncthreads();

        bf16x8 kf[4][2];
        #pragma unroll
        for (int n = 0; n < 4; ++n)
            #pragma unroll
            for (int c = 0; c < 2; ++c)
                kf[n][c] = *reinterpret_cast<const bf16x8*>(&Ks[n*16 + rr][c*32 + g8]);
        f32x4 sacc[2][4];
        #pragma unroll
        for (int m = 0; m < 2; ++m)
            #pragma unroll
            for (int n = 0; n < 4; ++n) sacc[m][n] = (f32x4){0.f,0.f,0.f,0.f};
        #pragma unroll
        for (int m = 0; m < 2; ++m)
            #pragma unroll
            for (int n = 0; n < 4; ++n)
                #pragma unroll
                for (int c = 0; c < 2; ++c)
                    sacc[m][n] = __builtin_amdgcn_mfma_f32_16x16x32_bf16(qf[m][c], kf[n][c], sacc[m][n], 0, 0, 0);

        float corr[2][4];
        #pragma unroll
        for (int m = 0; m < 2; ++m) {
            #pragma unroll
            for (int jj = 0; jj < 4; ++jj) {
                const int qg = qbase + w*32 + m*16 + g4 + jj;
                float pm = -1e30f;
                #pragma unroll
                for (int n = 0; n < 4; ++n) {
                    float v = sacc[m][n][jj] * 0.125f;
                    int jg = kt*64 + n*16 + rr;
                    v = (jg <= qg) ? v : -1e30f;
                    sacc[m][n][jj] = v;
                    pm = fmaxf(pm, v);
                }
                pm = fmaxf(pm, __shfl_xor(pm, 1, 64));
                pm = fmaxf(pm, __shfl_xor(pm, 2, 64));
                pm = fmaxf(pm, __shfl_xor(pm, 4, 64));
                pm = fmaxf(pm, __shfl_xor(pm, 8, 64));
                float nm = fmaxf(mst[m][jj], pm);
                float cv = __expf(mst[m][jj] - nm);
                float r = 0.f;
                #pragma unroll
                for (int n = 0; n < 4; ++n) {
                    float p = __expf(sacc[m][n][jj] - nm);
                    r += p;
                    Qs[w*32 + m*16 + g4 + jj][n*16 + rr] = __float2bfloat16(p);
                }
                r += __shfl_xor(r, 1, 64);
                r += __shfl_xor(r, 2, 64);
                r += __shfl_xor(r, 4, 64);
                r += __shfl_xor(r, 8, 64);
                lst[m][jj] = lst[m][jj] * cv + r;
                mst[m][jj] = nm;
                corr[m][jj] = cv;
            }
        }
        #pragma unroll
        for (int m = 0; m < 2; ++m)
            #pragma unroll
            for (int nd = 0; nd < 4; ++nd)
                #pragma unroll
                for (int jj = 0; jj < 4; ++jj) o[m][nd][jj] *= corr[m][jj];

        __builtin_amdgcn_sched_barrier(0);

        bf16x8 pf[2][2], vf[4][2];
        #pragma unroll
        for (int m = 0; m < 2; ++m)
            #pragma unroll
            for (int c = 0; c < 2; ++c)
                pf[m][c] = *reinterpret_cast<const bf16x8*>(&Qs[w*32 + m*16 + rr][c*32 + g8]);
        #pragma unroll
        for (int nd = 0; nd < 4; ++nd)
            #pragma unroll
            for (int c = 0; c < 2; ++c)
                vf[nd][c] = *reinterpret_cast<const bf16x8*>(&Vt[nd*16 + rr][c*32 + g8]);
        #pragma unroll
        for (int m = 0; m < 2; ++m)
            #pragma unroll
            for (int nd = 0; nd < 4; ++nd)
                #pragma unroll
                for (int c = 0; c < 2; ++c)
                    o[m][nd] = __builtin_amdgcn_mfma_f32_16x16x32_bf16(pf[m][c], vf[nd][c], o[m][nd], 0, 0, 0);
    }

    #pragma unroll
    for (int m = 0; m < 2; ++m) {
        #pragma unroll
        for (int jj = 0; jj < 4; ++jj) {
            const int qg = qbase + w*32 + m*16 + g4 + jj;
            const float inv = 1.0f / lst[m][jj];
            #pragma unroll
            for (int nd = 0; nd < 4; ++nd)
                ybf[(size_t)(b*TT + qg) * DD + h*64 + nd*16 + rr] =
                    __float2bfloat16(o[m][nd][jj] * inv);
        }
    }
}

// ---------------- host ----------------
extern "C" void kernel_launch(void* const* d_in, const int* in_sizes, int n_in,
                              void* d_out, int out_size, void* d_ws, size_t ws_size,
                              hipStream_t stream) {
    const int*   idx    = (const int*)  d_in[0];
    const float* wte    = (const float*)d_in[1];
    const float* wpe    = (const float*)d_in[2];
    const float* ln1_g  = (const float*)d_in[3];
    const float* ln1_b  = (const float*)d_in[4];
    const float* qkv_w  = (const float*)d_in[5];
    const float* qkv_b  = (const float*)d_in[6];
    const float* proj_w = (const float*)d_in[7];
    const float* proj_b = (const float*)d_in[8];
    const float* ln2_g  = (const float*)d_in[9];
    const float* ln2_b  = (const float*)d_in[10];
    const float* fc_w   = (const float*)d_in[11];
    const float* fc_b   = (const float*)d_in[12];
    const float* fc2_w  = (const float*)d_in[13];
    const float* fc2_b  = (const float*)d_in[14];
    const float* lnf_g  = (const float*)d_in[15];
    const float* lnf_b  = (const float*)d_in[16];

    char* ws = (char*)d_ws;
    size_t off = 0;
    auto alloc = [&](size_t bytes) -> void* {
        void* p = ws + off;
        off += (bytes + 255) & ~(size_t)255;
        return p;
    };
    float* x     = (float*)alloc((size_t)NTOK * DD * 4);
    bf16*  qkvb  = (bf16*) alloc((size_t)NTOK * 3 * DD * 2);
    bf16*  lnb   = (bf16*) alloc((size_t)NTOK * DD * 2);
    bf16*  ybf   = (bf16*) alloc((size_t)NTOK * DD * 2);
    bf16*  ffb   = (bf16*) alloc((size_t)NTOK * 4 * DD * 2);
    bf16*  w_qkv = (bf16*) alloc((size_t)NL * 3 * DD * DD * 2);
    bf16*  w_prj = (bf16*) alloc((size_t)NL * DD * DD * 2);
    bf16*  w_fc  = (bf16*) alloc((size_t)NL * 4 * DD * DD * 2);
    bf16*  w_fc2 = (bf16*) alloc((size_t)NL * DD * 4 * DD * 2);
    bf16*  w_wte = (bf16*) alloc((size_t)VV * DD * 2);

    // one fused cast dispatch for all weights
    {
        constexpr int totalBlocks = (VV*DD/4 + NL*3*DD*DD/4 + NL*DD*DD/4 +
                                     NL*4*DD*DD/4 + NL*DD*4*DD/4) / 256;
        cast_all<<<dim3(totalBlocks), dim3(256), 0, stream>>>(
            wte, qkv_w, proj_w, fc_w, fc2_w, w_wte, w_qkv, w_prj, w_fc, w_fc2);
    }

    embed_k<<<dim3(NTOK * (DD/4) / 256), dim3(256), 0, stream>>>(idx, wte, wpe, x);

    for (int l = 0; l < NL; ++l) {
        ln_k<<<dim3(NTOK), dim3(256), 0, stream>>>(x, ln1_g + l * DD, ln1_b + l * DD, lnb);
        gemm_bt<3,128><<<dim3(3 * DD / 128, 32), dim3(256), 0, stream>>>(
            lnb, w_qkv + (size_t)l * 3 * DD * DD, qkv_b + l * 3 * DD, nullptr,
            (void*)qkvb, 3 * DD, DD);
        attn_flash<<<dim3(24 * (TT / 128)), dim3(256), 0, stream>>>(qkvb, ybf);
        gemm_bt<1,64><<<dim3(DD / 64, 32), dim3(256), 0, stream>>>(
            ybf, w_prj + (size_t)l * DD * DD, proj_b + l * DD, x,
            (void*)x, DD, DD);
        ln_k<<<dim3(NTOK), dim3(256), 0, stream>>>(x, ln2_g + l * DD, ln2_b + l * DD, lnb);
        gemm_bt<2,128><<<dim3(4 * DD / 128, 32), dim3(256), 0, stream>>>(
            lnb, w_fc + (size_t)l * 4 * DD * DD, fc_b + l * 4 * DD, nullptr,
            (void*)ffb, 4 * DD, DD);
        gemm_bt<1,64><<<dim3(DD / 64, 32), dim3(256), 0, stream>>>(
            ffb, w_fc2 + (size_t)l * DD * 4 * DD, fc2_b + l * DD, x,
            (void*)x, DD, 4 * DD);
    }

    ln_k<<<dim3(NTOK), dim3(256), 0, stream>>>(x, lnf_g, lnf_b, lnb);
    gemm256<0, 1><<<dim3((VV / 256) * (NTOK / 256)), dim3(512), 0, stream>>>(
        lnb, w_wte, nullptr, nullptr, d_out, VV, DD, VV / 256);
}

// Round 15
// 755.663 us; speedup vs baseline: 1.3776x; 1.0585x over previous
//
#include <hip/hip_runtime.h>
#include <hip/hip_bf16.h>
#include <math.h>

#define BB 2
#define TT 2048
#define DD 768
#define HH 12
#define NTOK (BB*TT)   // 4096
#define VV 32000
#define NL 2

typedef __hip_bfloat16 bf16;
typedef __attribute__((ext_vector_type(8))) short bf16x8;
typedef __attribute__((ext_vector_type(4))) float f32x4;

typedef const __attribute__((address_space(1))) unsigned int* gas_u32;
typedef __attribute__((address_space(3))) unsigned int* las_u32;

__device__ __forceinline__ void gload16(const bf16* g, bf16* l) {
    __builtin_amdgcn_global_load_lds((gas_u32)g, (las_u32)l, 16, 0, 0);
}
__device__ __forceinline__ unsigned short f2bu(float f) {
    bf16 h = __float2bfloat16(f);
    return *reinterpret_cast<unsigned short*>(&h);
}

// ---------------- fused fp32 -> bf16 cast of ALL weights (one dispatch) ----------------
__global__ __launch_bounds__(256) void cast_all(
    const float* __restrict__ wte, const float* __restrict__ qkv_w,
    const float* __restrict__ proj_w, const float* __restrict__ fc_w,
    const float* __restrict__ fc2_w,
    bf16* __restrict__ o_wte, bf16* __restrict__ o_qkv, bf16* __restrict__ o_prj,
    bf16* __restrict__ o_fc, bf16* __restrict__ o_fc2)
{
    constexpr int N_WTE = VV * DD / 4;
    constexpr int N_QKV = NL * 3 * DD * DD / 4;
    constexpr int N_PRJ = NL * DD * DD / 4;
    constexpr int N_FC  = NL * 4 * DD * DD / 4;
    int g = blockIdx.x * 256 + threadIdx.x;
    const float* s; bf16* d;
    if (g < N_WTE) { s = wte; d = o_wte; }
    else if ((g -= N_WTE) < N_QKV) { s = qkv_w; d = o_qkv; }
    else if ((g -= N_QKV) < N_PRJ) { s = proj_w; d = o_prj; }
    else if ((g -= N_PRJ) < N_FC)  { s = fc_w;  d = o_fc; }
    else { g -= N_FC; s = fc2_w; d = o_fc2; }
    float4 v = reinterpret_cast<const float4*>(s)[g];
    ushort4 r;
    r.x = f2bu(v.x);
    r.y = f2bu(v.y);
    r.z = f2bu(v.z);
    r.w = f2bu(v.w);
    reinterpret_cast<ushort4*>(d)[g] = r;
}

// ---------------- embedding: x = wte[idx] + wpe[t] ----------------
__global__ void embed_k(const int* __restrict__ idx, const float* __restrict__ wte,
                        const float* __restrict__ wpe, float* __restrict__ x) {
    int i = blockIdx.x * 256 + threadIdx.x;          // over NTOK * (DD/4)
    int n = i / (DD/4), d4 = i - n * (DD/4);
    int tok = idx[n];
    int t = n & (TT - 1);
    float4 a = reinterpret_cast<const float4*>(wte + (size_t)tok * DD)[d4];
    float4 p = reinterpret_cast<const float4*>(wpe + (size_t)t * DD)[d4];
    float4 r; r.x = a.x+p.x; r.y = a.y+p.y; r.z = a.z+p.z; r.w = a.w+p.w;
    reinterpret_cast<float4*>(x)[i] = r;
}

// ---------------- LayerNorm: fp32 in -> bf16 out ----------------
__global__ __launch_bounds__(256) void ln_k(const float* __restrict__ x,
                                            const float* __restrict__ g,
                                            const float* __restrict__ b,
                                            bf16* __restrict__ out) {
    int row = blockIdx.x;
    int tid = threadIdx.x;
    const float* xr = x + (size_t)row * DD;
    float v0 = xr[tid], v1 = xr[tid + 256], v2 = xr[tid + 512];
    float s = v0 + v1 + v2;
    float ss = v0*v0 + v1*v1 + v2*v2;
    #pragma unroll
    for (int d = 1; d < 64; d <<= 1) { s += __shfl_xor(s, d, 64); ss += __shfl_xor(ss, d, 64); }
    __shared__ float sh[8];
    int w = tid >> 6;
    if ((tid & 63) == 0) { sh[w] = s; sh[4 + w] = ss; }
    __syncthreads();
    s  = sh[0] + sh[1] + sh[2] + sh[3];
    ss = sh[4] + sh[5] + sh[6] + sh[7];
    float mean = s * (1.0f / DD);
    float var  = ss * (1.0f / DD) - mean * mean;
    float rstd = rsqrtf(var + 1e-5f);
    bf16* orow = out + (size_t)row * DD;
    orow[tid]       = __float2bfloat16((v0 - mean) * rstd * g[tid]       + b[tid]);
    orow[tid + 256] = __float2bfloat16((v1 - mean) * rstd * g[tid + 256] + b[tid + 256]);
    orow[tid + 512] = __float2bfloat16((v2 - mean) * rstd * g[tid + 512] + b[tid + 512]);
}

// ================= 256x256 8-phase GEMM (lm-head) =================
// SWZMODE 1: XCD x gets chunk f in [x*250,(x+1)*250); by=f/125, bx=f%125 col-fastest.
// EPI 0 epilogue: LDS-transpose -> one 1KB contiguous NONTEMPORAL dwordx4 store per
// row (d_out is never re-read; keeping it out of L2/L3 preserves W residency).
template<int EPI, int SWZMODE>
__global__ __launch_bounds__(512, 1) void gemm256(
    const bf16* __restrict__ A, const bf16* __restrict__ W,
    const float* __restrict__ bias, const float* __restrict__ resid,
    void* __restrict__ outp, int O, int K, int nwgx)
{
    __shared__ bf16 smem_bf[65536];   // 128 KiB
    char* smem = (char*)smem_bf;
    const int tid = threadIdx.x, lane = tid & 63, wid = tid >> 6;
    const int wm = wid >> 2, wn = wid & 3;
    int f = blockIdx.x;
    if (SWZMODE == 1) { int x = f & 7, r = f >> 3; f = x * ((int)gridDim.x >> 3) + r; }
    const int by = f / nwgx;
    const int bx = f - by * nwgx;
    const int rowBase = by * 256, colBase = bx * 256;
    const int rr = lane & 15, s4 = lane >> 4;
    const int swz = (rr >> 1) & 3;
    const int aOff = (wm * 128 + rr) * 64 + ((s4 ^ swz) << 4);
    const int bOff = (wn * 64 + rr) * 64 + ((s4 ^ swz) << 4);
    const int st_r = (wid << 4) + (lane >> 2);
    const int st_j = lane & 3;
    const bf16* Asrc = A + (size_t)rowBase * K;
    const bf16* Wsrc = W + (size_t)colBase * K;
    const int nk = K >> 6;

    auto STAGE = [&](const bf16* src, int mat, int kt, int kk) {
        char* base = smem + ((kt & 1) << 16) + (mat << 15) + (kk << 14);
        #pragma unroll
        for (int L = 0; L < 2; ++L) {
            int r = (L << 7) + st_r;
            int gs = st_j ^ ((r >> 1) & 3);
            gload16(src + (size_t)r * K + (kt << 6) + (kk << 5) + (gs << 3),
                    (bf16*)(base + (L << 13) + (wid << 10)));
        }
    };

    f32x4 acc[8][4];
    #pragma unroll
    for (int m = 0; m < 8; ++m)
        #pragma unroll
        for (int n = 0; n < 4; ++n) acc[m][n] = (f32x4){0.f, 0.f, 0.f, 0.f};

    STAGE(Asrc, 0, 0, 0); STAGE(Wsrc, 1, 0, 0); STAGE(Asrc, 0, 0, 1); STAGE(Wsrc, 1, 0, 1);
    STAGE(Asrc, 0, 1, 0); STAGE(Wsrc, 1, 1, 0); STAGE(Asrc, 0, 1, 1);
    asm volatile("s_waitcnt vmcnt(6)" ::: "memory");
    __builtin_amdgcn_s_barrier();

    bf16x8 af[8], bfr[2];
    for (int kt = 0; kt < nk; ++kt) {
        char* Ab = smem + ((kt & 1) << 16);
        char* Bb = Ab + 32768;
        #pragma unroll
        for (int q = 0; q < 4; ++q) {
            const int kk = q >> 1, nh = q & 1;
            if (nh == 0) {
                #pragma unroll
                for (int m = 0; m < 8; ++m)
                    af[m] = *reinterpret_cast<const bf16x8*>(Ab + (kk << 14) + aOff + (m << 10));
            }
            bfr[0] = *reinterpret_cast<const bf16x8*>(Bb + (kk << 14) + bOff + ((nh * 2 + 0) << 10));
            bfr[1] = *reinterpret_cast<const bf16x8*>(Bb + (kk << 14) + bOff + ((nh * 2 + 1) << 10));
            if (q == 0) { if (kt + 1 < nk) STAGE(Wsrc, 1, kt + 1, 1); }
            else if (q == 1) { if (kt + 2 < nk) STAGE(Asrc, 0, kt + 2, 0); }
            else if (q == 2) { if (kt + 2 < nk) STAGE(Wsrc, 1, kt + 2, 0); }
            else { if (kt + 2 < nk) STAGE(Asrc, 0, kt + 2, 1); }
            __builtin_amdgcn_s_barrier();
            __builtin_amdgcn_s_setprio(1);
            #pragma unroll
            for (int m = 0; m < 8; ++m) {
                acc[m][nh * 2 + 0] = __builtin_amdgcn_mfma_f32_16x16x32_bf16(af[m], bfr[0], acc[m][nh * 2 + 0], 0, 0, 0);
                acc[m][nh * 2 + 1] = __builtin_amdgcn_mfma_f32_16x16x32_bf16(af[m], bfr[1], acc[m][nh * 2 + 1], 0, 0, 0);
            }
            __builtin_amdgcn_s_setprio(0);
            if (q == 3) {
                if (kt == nk - 2) asm volatile("s_waitcnt vmcnt(0)" ::: "memory");
                else              asm volatile("s_waitcnt vmcnt(6)" ::: "memory");
            }
            __builtin_amdgcn_s_barrier();
        }
    }

    if (EPI == 0) {
        float* outf = reinterpret_cast<float*>(outp);
        float* regf = reinterpret_cast<float*>(smem + wid * 4352);   // [16][68] f32
        #pragma unroll
        for (int m = 0; m < 8; ++m) {
            __syncthreads();
            #pragma unroll
            for (int n = 0; n < 4; ++n)
                #pragma unroll
                for (int j2 = 0; j2 < 4; ++j2)
                    regf[(s4 * 4 + j2) * 68 + n * 16 + rr] = acc[m][n][j2];
            __syncthreads();
            #pragma unroll
            for (int i = 0; i < 4; ++i) {
                int fr = wid + i * 8;
                int srcwid = (fr >> 4) * 4 + (lane >> 4);
                f32x4 v = *reinterpret_cast<const f32x4*>(
                    smem + srcwid * 4352 + (fr & 15) * 272 + (lane & 15) * 16);
                int grow = rowBase + (fr >> 4) * 128 + m * 16 + (fr & 15);
                __builtin_nontemporal_store(v,
                    reinterpret_cast<f32x4*>(&outf[(size_t)grow * O + colBase + lane * 4]));
            }
        }
        return;
    }

    #pragma unroll
    for (int m = 0; m < 8; ++m) {
        int row = rowBase + wm * 128 + m * 16 + s4 * 4;
        #pragma unroll
        for (int n = 0; n < 4; ++n) {
            int col = colBase + wn * 64 + n * 16 + rr;
            float bv = bias ? bias[col] : 0.f;
            #pragma unroll
            for (int j2 = 0; j2 < 4; ++j2) {
                float v = acc[m][n][j2] + bv;
                size_t oi = (size_t)(row + j2) * O + col;
                if (EPI == 1) v += resid[oi];
                if (EPI == 3) reinterpret_cast<bf16*>(outp)[oi] = __float2bfloat16(v);
                else          reinterpret_cast<float*>(outp)[oi] = v;
            }
        }
    }
}

// ---------------- GEMM 128xBN, BK=64 (half the barriers of BK=32) ----------------
// LDS rows are 128B (8 x 16B slots); slot swizzle slot' = slot ^ (row&7) applied as
// pre-swizzled GLOBAL source (st_row&7 == lane>>3) + swizzled read (row&7 == rr&7).
// Post-swizzle ds_read_b128 conflicts <= 2-way (free). Occupancy unchanged vs BK=32.
// EPI 1: f32+bias+resid  2: bf16+bias+gelu  3: bf16+bias
template<int EPI, int BN>
__global__ __launch_bounds__(256) void gemm_bt(
    const bf16* __restrict__ A, const bf16* __restrict__ W,
    const float* __restrict__ bias, const float* __restrict__ resid,
    void* __restrict__ outp, int O, int K)
{
    constexpr int NF = BN / 32;          // n-fragments per wave (4 or 2)
    __shared__ bf16 As[128 * 64];
    __shared__ bf16 Bs[BN * 64];
    const int tid = threadIdx.x;
    const int lane = tid & 63;
    const int w = tid >> 6;
    const int wm = w >> 1, wn = w & 1;
    const int rowBase = blockIdx.y * 128, colBase = blockIdx.x * BN;

    const int rr = lane & 15, s4 = lane >> 4;
    const int st_row = w * 8 + (lane >> 3);          // row within 32-row stripe group
    const int st_col = ((lane & 7) ^ (lane >> 3)) * 8;  // pre-swizzled global col
    const int r7 = rr & 7;                           // == row&7 for all fragment rows

    f32x4 acc[4][NF];
    #pragma unroll
    for (int m = 0; m < 4; ++m)
        #pragma unroll
        for (int n = 0; n < NF; ++n) acc[m][n] = (f32x4){0.f, 0.f, 0.f, 0.f};

    for (int k0 = 0; k0 < K; k0 += 64) {
        #pragma unroll
        for (int p = 0; p < 4; ++p)
            gload16(&A[(size_t)(rowBase + p * 32 + st_row) * K + k0 + st_col],
                    &As[(p * 32 + w * 8) * 64]);
        #pragma unroll
        for (int p = 0; p < BN / 32; ++p)
            gload16(&W[(size_t)(colBase + p * 32 + st_row) * K + k0 + st_col],
                    &Bs[(p * 32 + w * 8) * 64]);
        __syncthreads();
        #pragma unroll
        for (int kk = 0; kk < 2; ++kk) {
            const int slot = (kk * 4 + s4) ^ r7;     // swizzled 16B slot
            bf16x8 a[4], b[NF];
            #pragma unroll
            for (int m = 0; m < 4; ++m)
                a[m] = *reinterpret_cast<const bf16x8*>(&As[(wm * 64 + m * 16 + rr) * 64 + slot * 8]);
            #pragma unroll
            for (int n = 0; n < NF; ++n)
                b[n] = *reinterpret_cast<const bf16x8*>(&Bs[(wn * (BN/2) + n * 16 + rr) * 64 + slot * 8]);
            #pragma unroll
            for (int m = 0; m < 4; ++m)
                #pragma unroll
                for (int n = 0; n < NF; ++n)
                    acc[m][n] = __builtin_amdgcn_mfma_f32_16x16x32_bf16(a[m], b[n], acc[m][n], 0, 0, 0);
        }
        __syncthreads();
    }

    #pragma unroll
    for (int m = 0; m < 4; ++m) {
        int row = rowBase + wm * 64 + m * 16 + s4 * 4;
        #pragma unroll
        for (int n = 0; n < NF; ++n) {
            int col = colBase + wn * (BN/2) + n * 16 + rr;
            float bv = bias ? bias[col] : 0.f;
            #pragma unroll
            for (int j2 = 0; j2 < 4; ++j2) {
                float v = acc[m][n][j2] + bv;
                size_t oi = (size_t)(row + j2) * O + col;
                if (EPI == 1) v += resid[oi];
                if (EPI == 2) {
                    v = 0.5f * v * (1.0f + erff(v * 0.70710678118654752f));
                    reinterpret_cast<bf16*>(outp)[oi] = __float2bfloat16(v);
                } else if (EPI == 3) {
                    reinterpret_cast<bf16*>(outp)[oi] = __float2bfloat16(v);
                } else {
                    reinterpret_cast<float*>(outp)[oi] = v;
                }
            }
        }
    }
}

// ---------------- flash attention (R2/R6-proven version) ----------------
__global__ __launch_bounds__(256, 2) void attn_flash(const bf16* __restrict__ qkvb,
                                                     bf16* __restrict__ ybf)
{
    __shared__ bf16 Qs[128][72];   // Q tile; reused as P (wave w owns rows [w*32, w*32+32))
    __shared__ bf16 Ks[64][72];    // K tile  [j][d]
    __shared__ bf16 Vt[64][72];    // V tile transposed [d][j]

    const int tid = threadIdx.x, lane = tid & 63, w = tid >> 6;
    const int qi = 15 - (blockIdx.x / 24);          // big-work tiles first
    const int bh = blockIdx.x % 24;
    const int b = bh / HH, h = bh % HH;
    const int qbase = qi * 128;
    const int rr = lane & 15, g8 = (lane >> 4) * 8, g4 = (lane >> 4) * 4;

    {
        int seg = tid & 7, jr = tid >> 3;
        #pragma unroll
        for (int p = 0; p < 4; ++p) {
            int q = jr + p * 32;
            *reinterpret_cast<uint4*>(&Qs[q][seg * 8]) =
                *reinterpret_cast<const uint4*>(&qkvb[(size_t)(b*TT + qbase + q) * 2304 + h*64 + seg*8]);
        }
    }
    __syncthreads();

    bf16x8 qf[2][2];
    #pragma unroll
    for (int m = 0; m < 2; ++m)
        #pragma unroll
        for (int c = 0; c < 2; ++c)
            qf[m][c] = *reinterpret_cast<const bf16x8*>(&Qs[w*32 + m*16 + rr][c*32 + g8]);

    float mst[2][4], lst[2][4];
    f32x4 o[2][4];
    #pragma unroll
    for (int m = 0; m < 2; ++m)
        #pragma unroll
        for (int jj = 0; jj < 4; ++jj) { mst[m][jj] = -1e30f; lst[m][jj] = 0.f; }
    #pragma unroll
    for (int m = 0; m < 2; ++m)
        #pragma unroll
        for (int nd = 0; nd < 4; ++nd) o[m][nd] = (f32x4){0.f,0.f,0.f,0.f};

    const int ktmax = 2 * qi + 2;
    for (int kt = 0; kt < ktmax; ++kt) {
        __syncthreads();
        {
            int seg = tid & 7, jr = tid >> 3;
            #pragma unroll
            for (int p = 0; p < 2; ++p) {
                int j = jr + p * 32;
                *reinterpret_cast<uint4*>(&Ks[j][seg * 8]) =
                    *reinterpret_cast<const uint4*>(&qkvb[(size_t)(b*TT + kt*64 + j) * 2304 + DD + h*64 + seg*8]);
            }
            int jv = tid & 31, d0 = (tid >> 5) * 8;
            #pragma unroll
            for (int p = 0; p < 2; ++p) {
                int j = jv + p * 32;
                uint4 raw = *reinterpret_cast<const uint4*>(&qkvb[(size_t)(b*TT + kt*64 + j) * 2304 + 2*DD + h*64 + d0]);
                const bf16* vv = reinterpret_cast<const bf16*>(&raw);
                #pragma unroll
                for (int i2 = 0; i2 < 8; ++i2) Vt[d0 + i2][j] = vv[i2];
            }
        }
        __syncthreads();

        bf16x8 kf[4][2];
        #pragma unroll
        for (int n = 0; n < 4; ++n)
            #pragma unroll
            for (int c = 0; c < 2; ++c)
                kf[n][c] = *reinterpret_cast<const bf16x8*>(&Ks[n*16 + rr][c*32 + g8]);
        f32x4 sacc[2][4];
        #pragma unroll
        for (int m = 0; m < 2; ++m)
            #pragma unroll
            for (int n = 0; n < 4; ++n) sacc[m][n] = (f32x4){0.f,0.f,0.f,0.f};
        #pragma unroll
        for (int m = 0; m < 2; ++m)
            #pragma unroll
            for (int n = 0; n < 4; ++n)
                #pragma unroll
                for (int c = 0; c < 2; ++c)
                    sacc[m][n] = __builtin_amdgcn_mfma_f32_16x16x32_bf16(qf[m][c], kf[n][c], sacc[m][n], 0, 0, 0);

        float corr[2][4];
        #pragma unroll
        for (int m = 0; m < 2; ++m) {
            #pragma unroll
            for (int jj = 0; jj < 4; ++jj) {
                const int qg = qbase + w*32 + m*16 + g4 + jj;
                float pm = -1e30f;
                #pragma unroll
                for (int n = 0; n < 4; ++n) {
                    float v = sacc[m][n][jj] * 0.125f;
                    int jg = kt*64 + n*16 + rr;
                    v = (jg <= qg) ? v : -1e30f;
                    sacc[m][n][jj] = v;
                    pm = fmaxf(pm, v);
                }
                pm = fmaxf(pm, __shfl_xor(pm, 1, 64));
                pm = fmaxf(pm, __shfl_xor(pm, 2, 64));
                pm = fmaxf(pm, __shfl_xor(pm, 4, 64));
                pm = fmaxf(pm, __shfl_xor(pm, 8, 64));
                float nm = fmaxf(mst[m][jj], pm);
                float cv = __expf(mst[m][jj] - nm);
                float r = 0.f;
                #pragma unroll
                for (int n = 0; n < 4; ++n) {
                    float p = __expf(sacc[m][n][jj] - nm);
                    r += p;
                    Qs[w*32 + m*16 + g4 + jj][n*16 + rr] = __float2bfloat16(p);
                }
                r += __shfl_xor(r, 1, 64);
                r += __shfl_xor(r, 2, 64);
                r += __shfl_xor(r, 4, 64);
                r += __shfl_xor(r, 8, 64);
                lst[m][jj] = lst[m][jj] * cv + r;
                mst[m][jj] = nm;
                corr[m][jj] = cv;
            }
        }
        #pragma unroll
        for (int m = 0; m < 2; ++m)
            #pragma unroll
            for (int nd = 0; nd < 4; ++nd)
                #pragma unroll
                for (int jj = 0; jj < 4; ++jj) o[m][nd][jj] *= corr[m][jj];

        __builtin_amdgcn_sched_barrier(0);

        bf16x8 pf[2][2], vf[4][2];
        #pragma unroll
        for (int m = 0; m < 2; ++m)
            #pragma unroll
            for (int c = 0; c < 2; ++c)
                pf[m][c] = *reinterpret_cast<const bf16x8*>(&Qs[w*32 + m*16 + rr][c*32 + g8]);
        #pragma unroll
        for (int nd = 0; nd < 4; ++nd)
            #pragma unroll
            for (int c = 0; c < 2; ++c)
                vf[nd][c] = *reinterpret_cast<const bf16x8*>(&Vt[nd*16 + rr][c*32 + g8]);
        #pragma unroll
        for (int m = 0; m < 2; ++m)
            #pragma unroll
            for (int nd = 0; nd < 4; ++nd)
                #pragma unroll
                for (int c = 0; c < 2; ++c)
                    o[m][nd] = __builtin_amdgcn_mfma_f32_16x16x32_bf16(pf[m][c], vf[nd][c], o[m][nd], 0, 0, 0);
    }

    #pragma unroll
    for (int m = 0; m < 2; ++m) {
        #pragma unroll
        for (int jj = 0; jj < 4; ++jj) {
            const int qg = qbase + w*32 + m*16 + g4 + jj;
            const float inv = 1.0f / lst[m][jj];
            #pragma unroll
            for (int nd = 0; nd < 4; ++nd)
                ybf[(size_t)(b*TT + qg) * DD + h*64 + nd*16 + rr] =
                    __float2bfloat16(o[m][nd][jj] * inv);
        }
    }
}

// ---------------- host ----------------
extern "C" void kernel_launch(void* const* d_in, const int* in_sizes, int n_in,
                              void* d_out, int out_size, void* d_ws, size_t ws_size,
                              hipStream_t stream) {
    const int*   idx    = (const int*)  d_in[0];
    const float* wte    = (const float*)d_in[1];
    const float* wpe    = (const float*)d_in[2];
    const float* ln1_g  = (const float*)d_in[3];
    const float* ln1_b  = (const float*)d_in[4];
    const float* qkv_w  = (const float*)d_in[5];
    const float* qkv_b  = (const float*)d_in[6];
    const float* proj_w = (const float*)d_in[7];
    const float* proj_b = (const float*)d_in[8];
    const float* ln2_g  = (const float*)d_in[9];
    const float* ln2_b  = (const float*)d_in[10];
    const float* fc_w   = (const float*)d_in[11];
    const float* fc_b   = (const float*)d_in[12];
    const float* fc2_w  = (const float*)d_in[13];
    const float* fc2_b  = (const float*)d_in[14];
    const float* lnf_g  = (const float*)d_in[15];
    const float* lnf_b  = (const float*)d_in[16];

    char* ws = (char*)d_ws;
    size_t off = 0;
    auto alloc = [&](size_t bytes) -> void* {
        void* p = ws + off;
        off += (bytes + 255) & ~(size_t)255;
        return p;
    };
    float* x     = (float*)alloc((size_t)NTOK * DD * 4);
    bf16*  qkvb  = (bf16*) alloc((size_t)NTOK * 3 * DD * 2);
    bf16*  lnb   = (bf16*) alloc((size_t)NTOK * DD * 2);
    bf16*  ybf   = (bf16*) alloc((size_t)NTOK * DD * 2);
    bf16*  ffb   = (bf16*) alloc((size_t)NTOK * 4 * DD * 2);
    bf16*  w_qkv = (bf16*) alloc((size_t)NL * 3 * DD * DD * 2);
    bf16*  w_prj = (bf16*) alloc((size_t)NL * DD * DD * 2);
    bf16*  w_fc  = (bf16*) alloc((size_t)NL * 4 * DD * DD * 2);
    bf16*  w_fc2 = (bf16*) alloc((size_t)NL * DD * 4 * DD * 2);
    bf16*  w_wte = (bf16*) alloc((size_t)VV * DD * 2);

    // one fused cast dispatch for all weights
    {
        constexpr int totalBlocks = (VV*DD/4 + NL*3*DD*DD/4 + NL*DD*DD/4 +
                                     NL*4*DD*DD/4 + NL*DD*4*DD/4) / 256;
        cast_all<<<dim3(totalBlocks), dim3(256), 0, stream>>>(
            wte, qkv_w, proj_w, fc_w, fc2_w, w_wte, w_qkv, w_prj, w_fc, w_fc2);
    }

    embed_k<<<dim3(NTOK * (DD/4) / 256), dim3(256), 0, stream>>>(idx, wte, wpe, x);

    for (int l = 0; l < NL; ++l) {
        ln_k<<<dim3(NTOK), dim3(256), 0, stream>>>(x, ln1_g + l * DD, ln1_b + l * DD, lnb);
        gemm_bt<3,128><<<dim3(3 * DD / 128, 32), dim3(256), 0, stream>>>(
            lnb, w_qkv + (size_t)l * 3 * DD * DD, qkv_b + l * 3 * DD, nullptr,
            (void*)qkvb, 3 * DD, DD);
        attn_flash<<<dim3(24 * (TT / 128)), dim3(256), 0, stream>>>(qkvb, ybf);
        gemm_bt<1,64><<<dim3(DD / 64, 32), dim3(256), 0, stream>>>(
            ybf, w_prj + (size_t)l * DD * DD, proj_b + l * DD, x,
            (void*)x, DD, DD);
        ln_k<<<dim3(NTOK), dim3(256), 0, stream>>>(x, ln2_g + l * DD, ln2_b + l * DD, lnb);
        gemm_bt<2,128><<<dim3(4 * DD / 128, 32), dim3(256), 0, stream>>>(
            lnb, w_fc + (size_t)l * 4 * DD * DD, fc_b + l * 4 * DD, nullptr,
            (void*)ffb, 4 * DD, DD);
        gemm_bt<1,64><<<dim3(DD / 64, 32), dim3(256), 0, stream>>>(
            ffb, w_fc2 + (size_t)l * DD * 4 * DD, fc2_b + l * DD, x,
            (void*)x, DD, 4 * DD);
    }

    ln_k<<<dim3(NTOK), dim3(256), 0, stream>>>(x, lnf_g, lnf_b, lnb);
    gemm256<0, 1><<<dim3((VV / 256) * (NTOK / 256)), dim3(512), 0, stream>>>(
        lnb, w_wte, nullptr, nullptr, d_out, VV, DD, VV / 256);
}

// Round 16
// 752.068 us; speedup vs baseline: 1.3842x; 1.0048x over previous
//
#include <hip/hip_runtime.h>
#include <hip/hip_bf16.h>
#include <math.h>

#define BB 2
#define TT 2048
#define DD 768
#define HH 12
#define NTOK (BB*TT)   // 4096
#define VV 32000
#define NL 2

typedef __hip_bfloat16 bf16;
typedef __attribute__((ext_vector_type(8))) short bf16x8;
typedef __attribute__((ext_vector_type(4))) float f32x4;

typedef const __attribute__((address_space(1))) unsigned int* gas_u32;
typedef __attribute__((address_space(3))) unsigned int* las_u32;

__device__ __forceinline__ void gload16(const bf16* g, bf16* l) {
    __builtin_amdgcn_global_load_lds((gas_u32)g, (las_u32)l, 16, 0, 0);
}
__device__ __forceinline__ unsigned short f2bu(float f) {
    bf16 h = __float2bfloat16(f);
    return *reinterpret_cast<unsigned short*>(&h);
}

// ---------------- fused fp32 -> bf16 cast of ALL weights (one dispatch) ----------------
__global__ __launch_bounds__(256) void cast_all(
    const float* __restrict__ wte, const float* __restrict__ qkv_w,
    const float* __restrict__ proj_w, const float* __restrict__ fc_w,
    const float* __restrict__ fc2_w,
    bf16* __restrict__ o_wte, bf16* __restrict__ o_qkv, bf16* __restrict__ o_prj,
    bf16* __restrict__ o_fc, bf16* __restrict__ o_fc2)
{
    constexpr int N_WTE = VV * DD / 4;
    constexpr int N_QKV = NL * 3 * DD * DD / 4;
    constexpr int N_PRJ = NL * DD * DD / 4;
    constexpr int N_FC  = NL * 4 * DD * DD / 4;
    int g = blockIdx.x * 256 + threadIdx.x;
    const float* s; bf16* d;
    if (g < N_WTE) { s = wte; d = o_wte; }
    else if ((g -= N_WTE) < N_QKV) { s = qkv_w; d = o_qkv; }
    else if ((g -= N_QKV) < N_PRJ) { s = proj_w; d = o_prj; }
    else if ((g -= N_PRJ) < N_FC)  { s = fc_w;  d = o_fc; }
    else { g -= N_FC; s = fc2_w; d = o_fc2; }
    float4 v = reinterpret_cast<const float4*>(s)[g];
    ushort4 r;
    r.x = f2bu(v.x);
    r.y = f2bu(v.y);
    r.z = f2bu(v.z);
    r.w = f2bu(v.w);
    reinterpret_cast<ushort4*>(d)[g] = r;
}

// ---------------- embedding: x = wte[idx] + wpe[t] ----------------
__global__ void embed_k(const int* __restrict__ idx, const float* __restrict__ wte,
                        const float* __restrict__ wpe, float* __restrict__ x) {
    int i = blockIdx.x * 256 + threadIdx.x;          // over NTOK * (DD/4)
    int n = i / (DD/4), d4 = i - n * (DD/4);
    int tok = idx[n];
    int t = n & (TT - 1);
    float4 a = reinterpret_cast<const float4*>(wte + (size_t)tok * DD)[d4];
    float4 p = reinterpret_cast<const float4*>(wpe + (size_t)t * DD)[d4];
    float4 r; r.x = a.x+p.x; r.y = a.y+p.y; r.z = a.z+p.z; r.w = a.w+p.w;
    reinterpret_cast<float4*>(x)[i] = r;
}

// ---------------- LayerNorm: fp32 in -> bf16 out ----------------
__global__ __launch_bounds__(256) void ln_k(const float* __restrict__ x,
                                            const float* __restrict__ g,
                                            const float* __restrict__ b,
                                            bf16* __restrict__ out) {
    int row = blockIdx.x;
    int tid = threadIdx.x;
    const float* xr = x + (size_t)row * DD;
    float v0 = xr[tid], v1 = xr[tid + 256], v2 = xr[tid + 512];
    float s = v0 + v1 + v2;
    float ss = v0*v0 + v1*v1 + v2*v2;
    #pragma unroll
    for (int d = 1; d < 64; d <<= 1) { s += __shfl_xor(s, d, 64); ss += __shfl_xor(ss, d, 64); }
    __shared__ float sh[8];
    int w = tid >> 6;
    if ((tid & 63) == 0) { sh[w] = s; sh[4 + w] = ss; }
    __syncthreads();
    s  = sh[0] + sh[1] + sh[2] + sh[3];
    ss = sh[4] + sh[5] + sh[6] + sh[7];
    float mean = s * (1.0f / DD);
    float var  = ss * (1.0f / DD) - mean * mean;
    float rstd = rsqrtf(var + 1e-5f);
    bf16* orow = out + (size_t)row * DD;
    orow[tid]       = __float2bfloat16((v0 - mean) * rstd * g[tid]       + b[tid]);
    orow[tid + 256] = __float2bfloat16((v1 - mean) * rstd * g[tid + 256] + b[tid + 256]);
    orow[tid + 512] = __float2bfloat16((v2 - mean) * rstd * g[tid + 512] + b[tid + 512]);
}

// ================= 256x256 8-phase GEMM (lm-head) =================
// SWZMODE 1: XCD x gets chunk f in [x*250,(x+1)*250); by=f/125, bx=f%125 col-fastest.
// EPI 0 epilogue: LDS-transpose -> one 1KB contiguous NONTEMPORAL dwordx4 store per
// row (d_out is never re-read; keeping it out of L2/L3 preserves W residency).
template<int EPI, int SWZMODE>
__global__ __launch_bounds__(512, 1) void gemm256(
    const bf16* __restrict__ A, const bf16* __restrict__ W,
    const float* __restrict__ bias, const float* __restrict__ resid,
    void* __restrict__ outp, int O, int K, int nwgx)
{
    __shared__ bf16 smem_bf[65536];   // 128 KiB
    char* smem = (char*)smem_bf;
    const int tid = threadIdx.x, lane = tid & 63, wid = tid >> 6;
    const int wm = wid >> 2, wn = wid & 3;
    int f = blockIdx.x;
    if (SWZMODE == 1) { int x = f & 7, r = f >> 3; f = x * ((int)gridDim.x >> 3) + r; }
    const int by = f / nwgx;
    const int bx = f - by * nwgx;
    const int rowBase = by * 256, colBase = bx * 256;
    const int rr = lane & 15, s4 = lane >> 4;
    const int swz = (rr >> 1) & 3;
    const int aOff = (wm * 128 + rr) * 64 + ((s4 ^ swz) << 4);
    const int bOff = (wn * 64 + rr) * 64 + ((s4 ^ swz) << 4);
    const int st_r = (wid << 4) + (lane >> 2);
    const int st_j = lane & 3;
    const bf16* Asrc = A + (size_t)rowBase * K;
    const bf16* Wsrc = W + (size_t)colBase * K;
    const int nk = K >> 6;

    auto STAGE = [&](const bf16* src, int mat, int kt, int kk) {
        char* base = smem + ((kt & 1) << 16) + (mat << 15) + (kk << 14);
        #pragma unroll
        for (int L = 0; L < 2; ++L) {
            int r = (L << 7) + st_r;
            int gs = st_j ^ ((r >> 1) & 3);
            gload16(src + (size_t)r * K + (kt << 6) + (kk << 5) + (gs << 3),
                    (bf16*)(base + (L << 13) + (wid << 10)));
        }
    };

    f32x4 acc[8][4];
    #pragma unroll
    for (int m = 0; m < 8; ++m)
        #pragma unroll
        for (int n = 0; n < 4; ++n) acc[m][n] = (f32x4){0.f, 0.f, 0.f, 0.f};

    STAGE(Asrc, 0, 0, 0); STAGE(Wsrc, 1, 0, 0); STAGE(Asrc, 0, 0, 1); STAGE(Wsrc, 1, 0, 1);
    STAGE(Asrc, 0, 1, 0); STAGE(Wsrc, 1, 1, 0); STAGE(Asrc, 0, 1, 1);
    asm volatile("s_waitcnt vmcnt(6)" ::: "memory");
    __builtin_amdgcn_s_barrier();

    bf16x8 af[8], bfr[2];
    for (int kt = 0; kt < nk; ++kt) {
        char* Ab = smem + ((kt & 1) << 16);
        char* Bb = Ab + 32768;
        #pragma unroll
        for (int q = 0; q < 4; ++q) {
            const int kk = q >> 1, nh = q & 1;
            if (nh == 0) {
                #pragma unroll
                for (int m = 0; m < 8; ++m)
                    af[m] = *reinterpret_cast<const bf16x8*>(Ab + (kk << 14) + aOff + (m << 10));
            }
            bfr[0] = *reinterpret_cast<const bf16x8*>(Bb + (kk << 14) + bOff + ((nh * 2 + 0) << 10));
            bfr[1] = *reinterpret_cast<const bf16x8*>(Bb + (kk << 14) + bOff + ((nh * 2 + 1) << 10));
            if (q == 0) { if (kt + 1 < nk) STAGE(Wsrc, 1, kt + 1, 1); }
            else if (q == 1) { if (kt + 2 < nk) STAGE(Asrc, 0, kt + 2, 0); }
            else if (q == 2) { if (kt + 2 < nk) STAGE(Wsrc, 1, kt + 2, 0); }
            else { if (kt + 2 < nk) STAGE(Asrc, 0, kt + 2, 1); }
            __builtin_amdgcn_s_barrier();
            __builtin_amdgcn_s_setprio(1);
            #pragma unroll
            for (int m = 0; m < 8; ++m) {
                acc[m][nh * 2 + 0] = __builtin_amdgcn_mfma_f32_16x16x32_bf16(af[m], bfr[0], acc[m][nh * 2 + 0], 0, 0, 0);
                acc[m][nh * 2 + 1] = __builtin_amdgcn_mfma_f32_16x16x32_bf16(af[m], bfr[1], acc[m][nh * 2 + 1], 0, 0, 0);
            }
            __builtin_amdgcn_s_setprio(0);
            if (q == 3) {
                if (kt == nk - 2) asm volatile("s_waitcnt vmcnt(0)" ::: "memory");
                else              asm volatile("s_waitcnt vmcnt(6)" ::: "memory");
            }
            __builtin_amdgcn_s_barrier();
        }
    }

    if (EPI == 0) {
        float* outf = reinterpret_cast<float*>(outp);
        float* regf = reinterpret_cast<float*>(smem + wid * 4352);   // [16][68] f32
        #pragma unroll
        for (int m = 0; m < 8; ++m) {
            __syncthreads();
            #pragma unroll
            for (int n = 0; n < 4; ++n)
                #pragma unroll
                for (int j2 = 0; j2 < 4; ++j2)
                    regf[(s4 * 4 + j2) * 68 + n * 16 + rr] = acc[m][n][j2];
            __syncthreads();
            #pragma unroll
            for (int i = 0; i < 4; ++i) {
                int fr = wid + i * 8;
                int srcwid = (fr >> 4) * 4 + (lane >> 4);
                f32x4 v = *reinterpret_cast<const f32x4*>(
                    smem + srcwid * 4352 + (fr & 15) * 272 + (lane & 15) * 16);
                int grow = rowBase + (fr >> 4) * 128 + m * 16 + (fr & 15);
                __builtin_nontemporal_store(v,
                    reinterpret_cast<f32x4*>(&outf[(size_t)grow * O + colBase + lane * 4]));
            }
        }
        return;
    }

    #pragma unroll
    for (int m = 0; m < 8; ++m) {
        int row = rowBase + wm * 128 + m * 16 + s4 * 4;
        #pragma unroll
        for (int n = 0; n < 4; ++n) {
            int col = colBase + wn * 64 + n * 16 + rr;
            float bv = bias ? bias[col] : 0.f;
            #pragma unroll
            for (int j2 = 0; j2 < 4; ++j2) {
                float v = acc[m][n][j2] + bv;
                size_t oi = (size_t)(row + j2) * O + col;
                if (EPI == 1) v += resid[oi];
                if (EPI == 3) reinterpret_cast<bf16*>(outp)[oi] = __float2bfloat16(v);
                else          reinterpret_cast<float*>(outp)[oi] = v;
            }
        }
    }
}

// ---------------- GEMM 128xBN, BK=64, slot-swizzled LDS ----------------
// BN=128 (qkv/fc): single-buffered (grids 576/768 blocks -> TLP hides staging).
// BN=64 (proj/fc2): DOUBLE-BUFFERED 2-phase counted-vmcnt (grids 384 blocks = 1.5
// blocks/CU actual -> no TLP; dbuf LDS 48KB caps at 3 blocks/CU >= actual, no loss).
// Swizzle: slot' = slot ^ (row&7), pre-swizzled global source + swizzled read.
// EPI 1: f32+bias+resid  2: bf16+bias+gelu  3: bf16+bias
template<int EPI, int BN>
__global__ __launch_bounds__(256) void gemm_bt(
    const bf16* __restrict__ A, const bf16* __restrict__ W,
    const float* __restrict__ bias, const float* __restrict__ resid,
    void* __restrict__ outp, int O, int K)
{
    constexpr int NF = BN / 32;          // n-fragments per wave (4 or 2)
    constexpr bool PIPE = (BN == 64);
    __shared__ bf16 As[(PIPE ? 2 : 1) * 128 * 64];
    __shared__ bf16 Bs[(PIPE ? 2 : 1) * BN * 64];
    const int tid = threadIdx.x;
    const int lane = tid & 63;
    const int w = tid >> 6;
    const int wm = w >> 1, wn = w & 1;
    const int rowBase = blockIdx.y * 128, colBase = blockIdx.x * BN;

    const int rr = lane & 15, s4 = lane >> 4;
    const int st_row = w * 8 + (lane >> 3);          // row within 32-row stripe group
    const int st_col = ((lane & 7) ^ (lane >> 3)) * 8;  // pre-swizzled global col
    const int r7 = rr & 7;                           // == row&7 for all fragment rows

    f32x4 acc[4][NF];
    #pragma unroll
    for (int m = 0; m < 4; ++m)
        #pragma unroll
        for (int n = 0; n < NF; ++n) acc[m][n] = (f32x4){0.f, 0.f, 0.f, 0.f};

    // stage tile kt into buffer b
    auto STAGE = [&](int b, int k0) {
        #pragma unroll
        for (int p = 0; p < 4; ++p)
            gload16(&A[(size_t)(rowBase + p * 32 + st_row) * K + k0 + st_col],
                    &As[b * (128 * 64) + (p * 32 + w * 8) * 64]);
        #pragma unroll
        for (int p = 0; p < BN / 32; ++p)
            gload16(&W[(size_t)(colBase + p * 32 + st_row) * K + k0 + st_col],
                    &Bs[b * (BN * 64) + (p * 32 + w * 8) * 64]);
    };
    auto COMPUTE = [&](int b) {
        #pragma unroll
        for (int kk = 0; kk < 2; ++kk) {
            const int slot = (kk * 4 + s4) ^ r7;     // swizzled 16B slot
            bf16x8 a[4], bb[NF];
            #pragma unroll
            for (int m = 0; m < 4; ++m)
                a[m] = *reinterpret_cast<const bf16x8*>(
                    &As[b * (128 * 64) + (wm * 64 + m * 16 + rr) * 64 + slot * 8]);
            #pragma unroll
            for (int n = 0; n < NF; ++n)
                bb[n] = *reinterpret_cast<const bf16x8*>(
                    &Bs[b * (BN * 64) + (wn * (BN/2) + n * 16 + rr) * 64 + slot * 8]);
            #pragma unroll
            for (int m = 0; m < 4; ++m)
                #pragma unroll
                for (int n = 0; n < NF; ++n)
                    acc[m][n] = __builtin_amdgcn_mfma_f32_16x16x32_bf16(a[m], bb[n], acc[m][n], 0, 0, 0);
        }
    };

    if constexpr (PIPE) {
        const int nk = K >> 6;
        STAGE(0, 0);                               // 6 loads in flight
        for (int kt = 0; kt < nk; ++kt) {
            const int cur = kt & 1;
            if (kt + 1 < nk) {
                STAGE(cur ^ 1, (kt + 1) << 6);     // +6 loads -> 12 in flight
                asm volatile("s_waitcnt vmcnt(6)" ::: "memory");   // tile kt landed
            } else {
                asm volatile("s_waitcnt vmcnt(0)" ::: "memory");
            }
            __builtin_amdgcn_s_barrier();          // all waves' tile-kt stages done
            __builtin_amdgcn_s_setprio(1);
            COMPUTE(cur);
            __builtin_amdgcn_s_setprio(0);
            __builtin_amdgcn_s_barrier();          // reads done before buf reuse (kt+2)
        }
    } else {
        for (int k0 = 0; k0 < K; k0 += 64) {
            STAGE(0, k0);
            __syncthreads();
            COMPUTE(0);
            __syncthreads();
        }
    }

    #pragma unroll
    for (int m = 0; m < 4; ++m) {
        int row = rowBase + wm * 64 + m * 16 + s4 * 4;
        #pragma unroll
        for (int n = 0; n < NF; ++n) {
            int col = colBase + wn * (BN/2) + n * 16 + rr;
            float bv = bias ? bias[col] : 0.f;
            #pragma unroll
            for (int j2 = 0; j2 < 4; ++j2) {
                float v = acc[m][n][j2] + bv;
                size_t oi = (size_t)(row + j2) * O + col;
                if (EPI == 1) v += resid[oi];
                if (EPI == 2) {
                    v = 0.5f * v * (1.0f + erff(v * 0.70710678118654752f));
                    reinterpret_cast<bf16*>(outp)[oi] = __float2bfloat16(v);
                } else if (EPI == 3) {
                    reinterpret_cast<bf16*>(outp)[oi] = __float2bfloat16(v);
                } else {
                    reinterpret_cast<float*>(outp)[oi] = v;
                }
            }
        }
    }
}

// ---------------- flash attention (R2/R6-proven version) ----------------
__global__ __launch_bounds__(256, 2) void attn_flash(const bf16* __restrict__ qkvb,
                                                     bf16* __restrict__ ybf)
{
    __shared__ bf16 Qs[128][72];   // Q tile; reused as P (wave w owns rows [w*32, w*32+32))
    __shared__ bf16 Ks[64][72];    // K tile  [j][d]
    __shared__ bf16 Vt[64][72];    // V tile transposed [d][j]

    const int tid = threadIdx.x, lane = tid & 63, w = tid >> 6;
    const int qi = 15 - (blockIdx.x / 24);          // big-work tiles first
    const int bh = blockIdx.x % 24;
    const int b = bh / HH, h = bh % HH;
    const int qbase = qi * 128;
    const int rr = lane & 15, g8 = (lane >> 4) * 8, g4 = (lane >> 4) * 4;

    {
        int seg = tid & 7, jr = tid >> 3;
        #pragma unroll
        for (int p = 0; p < 4; ++p) {
            int q = jr + p * 32;
            *reinterpret_cast<uint4*>(&Qs[q][seg * 8]) =
                *reinterpret_cast<const uint4*>(&qkvb[(size_t)(b*TT + qbase + q) * 2304 + h*64 + seg*8]);
        }
    }
    __syncthreads();

    bf16x8 qf[2][2];
    #pragma unroll
    for (int m = 0; m < 2; ++m)
        #pragma unroll
        for (int c = 0; c < 2; ++c)
            qf[m][c] = *reinterpret_cast<const bf16x8*>(&Qs[w*32 + m*16 + rr][c*32 + g8]);

    float mst[2][4], lst[2][4];
    f32x4 o[2][4];
    #pragma unroll
    for (int m = 0; m < 2; ++m)
        #pragma unroll
        for (int jj = 0; jj < 4; ++jj) { mst[m][jj] = -1e30f; lst[m][jj] = 0.f; }
    #pragma unroll
    for (int m = 0; m < 2; ++m)
        #pragma unroll
        for (int nd = 0; nd < 4; ++nd) o[m][nd] = (f32x4){0.f,0.f,0.f,0.f};

    const int ktmax = 2 * qi + 2;
    for (int kt = 0; kt < ktmax; ++kt) {
        __syncthreads();
        {
            int seg = tid & 7, jr = tid >> 3;
            #pragma unroll
            for (int p = 0; p < 2; ++p) {
                int j = jr + p * 32;
                *reinterpret_cast<uint4*>(&Ks[j][seg * 8]) =
                    *reinterpret_cast<const uint4*>(&qkvb[(size_t)(b*TT + kt*64 + j) * 2304 + DD + h*64 + seg*8]);
            }
            int jv = tid & 31, d0 = (tid >> 5) * 8;
            #pragma unroll
            for (int p = 0; p < 2; ++p) {
                int j = jv + p * 32;
                uint4 raw = *reinterpret_cast<const uint4*>(&qkvb[(size_t)(b*TT + kt*64 + j) * 2304 + 2*DD + h*64 + d0]);
                const bf16* vv = reinterpret_cast<const bf16*>(&raw);
                #pragma unroll
                for (int i2 = 0; i2 < 8; ++i2) Vt[d0 + i2][j] = vv[i2];
            }
        }
        __syncthreads();

        bf16x8 kf[4][2];
        #pragma unroll
        for (int n = 0; n < 4; ++n)
            #pragma unroll
            for (int c = 0; c < 2; ++c)
                kf[n][c] = *reinterpret_cast<const bf16x8*>(&Ks[n*16 + rr][c*32 + g8]);
        f32x4 sacc[2][4];
        #pragma unroll
        for (int m = 0; m < 2; ++m)
            #pragma unroll
            for (int n = 0; n < 4; ++n) sacc[m][n] = (f32x4){0.f,0.f,0.f,0.f};
        #pragma unroll
        for (int m = 0; m < 2; ++m)
            #pragma unroll
            for (int n = 0; n < 4; ++n)
                #pragma unroll
                for (int c = 0; c < 2; ++c)
                    sacc[m][n] = __builtin_amdgcn_mfma_f32_16x16x32_bf16(qf[m][c], kf[n][c], sacc[m][n], 0, 0, 0);

        float corr[2][4];
        #pragma unroll
        for (int m = 0; m < 2; ++m) {
            #pragma unroll
            for (int jj = 0; jj < 4; ++jj) {
                const int qg = qbase + w*32 + m*16 + g4 + jj;
                float pm = -1e30f;
                #pragma unroll
                for (int n = 0; n < 4; ++n) {
                    float v = sacc[m][n][jj] * 0.125f;
                    int jg = kt*64 + n*16 + rr;
                    v = (jg <= qg) ? v : -1e30f;
                    sacc[m][n][jj] = v;
                    pm = fmaxf(pm, v);
                }
                pm = fmaxf(pm, __shfl_xor(pm, 1, 64));
                pm = fmaxf(pm, __shfl_xor(pm, 2, 64));
                pm = fmaxf(pm, __shfl_xor(pm, 4, 64));
                pm = fmaxf(pm, __shfl_xor(pm, 8, 64));
                float nm = fmaxf(mst[m][jj], pm);
                float cv = __expf(mst[m][jj] - nm);
                float r = 0.f;
                #pragma unroll
                for (int n = 0; n < 4; ++n) {
                    float p = __expf(sacc[m][n][jj] - nm);
                    r += p;
                    Qs[w*32 + m*16 + g4 + jj][n*16 + rr] = __float2bfloat16(p);
                }
                r += __shfl_xor(r, 1, 64);
                r += __shfl_xor(r, 2, 64);
                r += __shfl_xor(r, 4, 64);
                r += __shfl_xor(r, 8, 64);
                lst[m][jj] = lst[m][jj] * cv + r;
                mst[m][jj] = nm;
                corr[m][jj] = cv;
            }
        }
        #pragma unroll
        for (int m = 0; m < 2; ++m)
            #pragma unroll
            for (int nd = 0; nd < 4; ++nd)
                #pragma unroll
                for (int jj = 0; jj < 4; ++jj) o[m][nd][jj] *= corr[m][jj];

        __builtin_amdgcn_sched_barrier(0);

        bf16x8 pf[2][2], vf[4][2];
        #pragma unroll
        for (int m = 0; m < 2; ++m)
            #pragma unroll
            for (int c = 0; c < 2; ++c)
                pf[m][c] = *reinterpret_cast<const bf16x8*>(&Qs[w*32 + m*16 + rr][c*32 + g8]);
        #pragma unroll
        for (int nd = 0; nd < 4; ++nd)
            #pragma unroll
            for (int c = 0; c < 2; ++c)
                vf[nd][c] = *reinterpret_cast<const bf16x8*>(&Vt[nd*16 + rr][c*32 + g8]);
        #pragma unroll
        for (int m = 0; m < 2; ++m)
            #pragma unroll
            for (int nd = 0; nd < 4; ++nd)
                #pragma unroll
                for (int c = 0; c < 2; ++c)
                    o[m][nd] = __builtin_amdgcn_mfma_f32_16x16x32_bf16(pf[m][c], vf[nd][c], o[m][nd], 0, 0, 0);
    }

    #pragma unroll
    for (int m = 0; m < 2; ++m) {
        #pragma unroll
        for (int jj = 0; jj < 4; ++jj) {
            const int qg = qbase + w*32 + m*16 + g4 + jj;
            const float inv = 1.0f / lst[m][jj];
            #pragma unroll
            for (int nd = 0; nd < 4; ++nd)
                ybf[(size_t)(b*TT + qg) * DD + h*64 + nd*16 + rr] =
                    __float2bfloat16(o[m][nd][jj] * inv);
        }
    }
}

// ---------------- host ----------------
extern "C" void kernel_launch(void* const* d_in, const int* in_sizes, int n_in,
                              void* d_out, int out_size, void* d_ws, size_t ws_size,
                              hipStream_t stream) {
    const int*   idx    = (const int*)  d_in[0];
    const float* wte    = (const float*)d_in[1];
    const float* wpe    = (const float*)d_in[2];
    const float* ln1_g  = (const float*)d_in[3];
    const float* ln1_b  = (const float*)d_in[4];
    const float* qkv_w  = (const float*)d_in[5];
    const float* qkv_b  = (const float*)d_in[6];
    const float* proj_w = (const float*)d_in[7];
    const float* proj_b = (const float*)d_in[8];
    const float* ln2_g  = (const float*)d_in[9];
    const float* ln2_b  = (const float*)d_in[10];
    const float* fc_w   = (const float*)d_in[11];
    const float* fc_b   = (const float*)d_in[12];
    const float* fc2_w  = (const float*)d_in[13];
    const float* fc2_b  = (const float*)d_in[14];
    const float* lnf_g  = (const float*)d_in[15];
    const float* lnf_b  = (const float*)d_in[16];

    char* ws = (char*)d_ws;
    size_t off = 0;
    auto alloc = [&](size_t bytes) -> void* {
        void* p = ws + off;
        off += (bytes + 255) & ~(size_t)255;
        return p;
    };
    float* x     = (float*)alloc((size_t)NTOK * DD * 4);
    bf16*  qkvb  = (bf16*) alloc((size_t)NTOK * 3 * DD * 2);
    bf16*  lnb   = (bf16*) alloc((size_t)NTOK * DD * 2);
    bf16*  ybf   = (bf16*) alloc((size_t)NTOK * DD * 2);
    bf16*  ffb   = (bf16*) alloc((size_t)NTOK * 4 * DD * 2);
    bf16*  w_qkv = (bf16*) alloc((size_t)NL * 3 * DD * DD * 2);
    bf16*  w_prj = (bf16*) alloc((size_t)NL * DD * DD * 2);
    bf16*  w_fc  = (bf16*) alloc((size_t)NL * 4 * DD * DD * 2);
    bf16*  w_fc2 = (bf16*) alloc((size_t)NL * DD * 4 * DD * 2);
    bf16*  w_wte = (bf16*) alloc((size_t)VV * DD * 2);

    // one fused cast dispatch for all weights
    {
        constexpr int totalBlocks = (VV*DD/4 + NL*3*DD*DD/4 + NL*DD*DD/4 +
                                     NL*4*DD*DD/4 + NL*DD*4*DD/4) / 256;
        cast_all<<<dim3(totalBlocks), dim3(256), 0, stream>>>(
            wte, qkv_w, proj_w, fc_w, fc2_w, w_wte, w_qkv, w_prj, w_fc, w_fc2);
    }

    embed_k<<<dim3(NTOK * (DD/4) / 256), dim3(256), 0, stream>>>(idx, wte, wpe, x);

    for (int l = 0; l < NL; ++l) {
        ln_k<<<dim3(NTOK), dim3(256), 0, stream>>>(x, ln1_g + l * DD, ln1_b + l * DD, lnb);
        gemm_bt<3,128><<<dim3(3 * DD / 128, 32), dim3(256), 0, stream>>>(
            lnb, w_qkv + (size_t)l * 3 * DD * DD, qkv_b + l * 3 * DD, nullptr,
            (void*)qkvb, 3 * DD, DD);
        attn_flash<<<dim3(24 * (TT / 128)), dim3(256), 0, stream>>>(qkvb, ybf);
        gemm_bt<1,64><<<dim3(DD / 64, 32), dim3(256), 0, stream>>>(
            ybf, w_prj + (size_t)l * DD * DD, proj_b + l * DD, x,
            (void*)x, DD, DD);
        ln_k<<<dim3(NTOK), dim3(256), 0, stream>>>(x, ln2_g + l * DD, ln2_b + l * DD, lnb);
        gemm_bt<2,128><<<dim3(4 * DD / 128, 32), dim3(256), 0, stream>>>(
            lnb, w_fc + (size_t)l * 4 * DD * DD, fc_b + l * 4 * DD, nullptr,
            (void*)ffb, 4 * DD, DD);
        gemm_bt<1,64><<<dim3(DD / 64, 32), dim3(256), 0, stream>>>(
            ffb, w_fc2 + (size_t)l * DD * 4 * DD, fc2_b + l * DD, x,
            (void*)x, DD, 4 * DD);
    }

    ln_k<<<dim3(NTOK), dim3(256), 0, stream>>>(x, lnf_g, lnf_b, lnb);
    gemm256<0, 1><<<dim3((VV / 256) * (NTOK / 256)), dim3(512), 0, stream>>>(
        lnb, w_wte, nullptr, nullptr, d_out, VV, DD, VV / 256);
}